// Round 1
// baseline (2267.977 us; speedup 1.0000x reference)
//
#include <hip/hip_runtime.h>
#include <math.h>

#define D 128
#define BN_EPS 1e-5f

// ---------------------------------------------------------------- degree
__global__ void k_deg_init(float* deg, int n) {
  int i = blockIdx.x * blockDim.x + threadIdx.x;
  if (i < n) deg[i] = 1.0f;  // self-loop weight (PyG gcn_norm fill_value=1)
}

__global__ void k_deg_acc(const int* __restrict__ dst, const float* __restrict__ ew,
                          float* deg, int e) {
  int i = blockIdx.x * blockDim.x + threadIdx.x;
  if (i < e) atomicAdd(&deg[dst[i]], ew[i]);
}

__global__ void k_dinv(float* deg, int n) {
  int i = blockIdx.x * blockDim.x + threadIdx.x;
  if (i < n) {
    float d = deg[i];
    deg[i] = d > 0.f ? rsqrtf(fmaxf(d, 1e-30f)) : 0.f;  // in place -> dinv
  }
}

__global__ void k_edge_coef(const int* __restrict__ src, const int* __restrict__ dst,
                            const float* __restrict__ ew, const float* __restrict__ dinv,
                            float* __restrict__ c, int e) {
  int i = blockIdx.x * blockDim.x + threadIdx.x;
  if (i < e) c[i] = dinv[src[i]] * ew[i] * dinv[dst[i]];
}

// ---------------------------------------------------------------- GEMM h = X @ W
// X: [n,128], W: [128,128] row-major. Block: 256 threads -> 32 rows x 128 cols,
// thread owns one col and 16 rows (ty interleave). W staged in LDS in two
// k-halves (32KB) + 32 X rows (16KB) => 48KB LDS => 3 blocks/CU.
__global__ __launch_bounds__(256) void k_gemm(const float* __restrict__ X,
                                              const float* __restrict__ W,
                                              float* __restrict__ H, int n) {
  __shared__ float sW[64][D];   // 32 KB (one k-half)
  __shared__ float sX[32][D];   // 16 KB
  const int tid  = threadIdx.x;
  const int col  = tid & 127;
  const int ty   = tid >> 7;    // 0 or 1
  const int row0 = blockIdx.x * 32;

  for (int i = tid; i < 32 * D; i += 256) {
    int r = i >> 7;
    sX[r][i & 127] = (row0 + r < n) ? X[(size_t)(row0 + r) * D + (i & 127)] : 0.f;
  }

  float acc[16];
#pragma unroll
  for (int t = 0; t < 16; ++t) acc[t] = 0.f;

  for (int ph = 0; ph < 2; ++ph) {
    __syncthreads();  // sX ready / previous sW consumed
    for (int i = tid; i < 64 * D; i += 256)
      sW[i >> 7][i & 127] = W[(size_t)(ph * 64 + (i >> 7)) * D + (i & 127)];
    __syncthreads();
#pragma unroll 1
    for (int k = 0; k < 64; ++k) {
      float w = sW[k][col];          // 2 lanes/bank -> conflict-free
#pragma unroll
      for (int t = 0; t < 16; ++t)   // sX read is wave-uniform -> broadcast
        acc[t] += sX[2 * t + ty][ph * 64 + k] * w;
    }
  }
#pragma unroll
  for (int t = 0; t < 16; ++t) {
    int r = row0 + 2 * t + ty;
    if (r < n) H[(size_t)r * D + col] = acc[t];
  }
}

// ------------------------------------------------- self-loop init: A = H * dinv^2
__global__ void k_selfinit(const float* __restrict__ H, const float* __restrict__ dinv,
                           float* __restrict__ A, int n) {
  int i = blockIdx.x * blockDim.x + threadIdx.x;  // over n * D/4 float4s
  if (i < n * (D / 4)) {
    int r = i >> 5;  // 32 float4 per row
    float di = dinv[r];
    float coef = di * di;
    float4 v = ((const float4*)H)[i];
    v.x *= coef; v.y *= coef; v.z *= coef; v.w *= coef;
    ((float4*)A)[i] = v;
  }
}

// ------------------------------------------------- edge scatter: A[dst] += c * H[src]
// 32 lanes per edge, each lane owns 4 consecutive floats (float4 gather, 4 atomics).
__global__ void k_edge_agg(const int* __restrict__ src, const int* __restrict__ dst,
                           const float* __restrict__ c, const float* __restrict__ H,
                           float* A, int total) {
  int t = blockIdx.x * blockDim.x + threadIdx.x;
  if (t >= total) return;  // total = e * 32
  int e = t >> 5;
  int l = t & 31;
  int s = src[e], d = dst[e];
  float coef = c[e];
  float4 v = *(const float4*)(H + (size_t)s * D + l * 4);
  float* o = A + (size_t)d * D + l * 4;
  atomicAdd(o + 0, v.x * coef);
  atomicAdd(o + 1, v.y * coef);
  atomicAdd(o + 2, v.z * coef);
  atomicAdd(o + 3, v.w * coef);
}

// ------------------------------------------------- bias + BN(eval) [+ activation]
__global__ void k_post(float* __restrict__ A, const float* __restrict__ b,
                       const float* __restrict__ gamma, const float* __restrict__ beta,
                       const float* __restrict__ mean, const float* __restrict__ var,
                       const float* __restrict__ act_params, int with_act, int n) {
  int i = blockIdx.x * blockDim.x + threadIdx.x;
  if (i < n * D) {
    int j = i & 127;
    float v = A[i] + b[j];
    v = (v - mean[j]) * rsqrtf(var[j] + BN_EPS) * gamma[j] + beta[j];
    if (with_act) {
      float alpha = 1.f / (1.f + expf(-act_params[0]));
      float r = fmaxf(v, 0.f);
      float g = 0.5f * v * (1.f + erff(v * 0.70710678118654752f));
      v = alpha * r + (1.f - alpha) * g;
    }
    A[i] = v;
  }
}

// ---------------------------------------------------------------- launch
extern "C" void kernel_launch(void* const* d_in, const int* in_sizes, int n_in,
                              void* d_out, int out_size, void* d_ws, size_t ws_size,
                              hipStream_t stream) {
  const float* x      = (const float*)d_in[0];
  const int*   ei     = (const int*)d_in[1];
  const float* ew     = (const float*)d_in[2];
  const float* W0     = (const float*)d_in[3];
  const float* b0     = (const float*)d_in[4];
  const float* W1     = (const float*)d_in[5];
  const float* b1     = (const float*)d_in[6];
  const float* gamma0 = (const float*)d_in[7];
  const float* beta0  = (const float*)d_in[8];
  const float* mean0  = (const float*)d_in[9];
  const float* var0   = (const float*)d_in[10];
  const float* gamma1 = (const float*)d_in[11];
  const float* beta1  = (const float*)d_in[12];
  const float* mean1  = (const float*)d_in[13];
  const float* var1   = (const float*)d_in[14];
  const float* act    = (const float*)d_in[15];

  const int n = in_sizes[0] / D;
  const int e = in_sizes[2];
  const int* srcp = ei;
  const int* dstp = ei + e;

  float* ws   = (float*)d_ws;
  float* dinv = ws;                  // n
  float* c    = dinv + n;            // e
  float* h    = c + e;               // n*D
  float* a    = h + (size_t)n * D;   // n*D
  float* out  = (float*)d_out;

  const int tpb = 256;

  // shared degree -> dinv -> per-edge coefficient (reused by both layers)
  k_deg_init<<<(n + tpb - 1) / tpb, tpb, 0, stream>>>(dinv, n);
  k_deg_acc<<<(e + tpb - 1) / tpb, tpb, 0, stream>>>(dstp, ew, dinv, e);
  k_dinv<<<(n + tpb - 1) / tpb, tpb, 0, stream>>>(dinv, n);
  k_edge_coef<<<(e + tpb - 1) / tpb, tpb, 0, stream>>>(srcp, dstp, ew, dinv, c, e);

  // ---- layer 0: conv -> BN -> blended activation
  k_gemm<<<(n + 31) / 32, tpb, 0, stream>>>(x, W0, h, n);
  k_selfinit<<<(n * (D / 4) + tpb - 1) / tpb, tpb, 0, stream>>>(h, dinv, a, n);
  k_edge_agg<<<(e * 32 + tpb - 1) / tpb, tpb, 0, stream>>>(srcp, dstp, c, h, a, e * 32);
  k_post<<<(n * D + tpb - 1) / tpb, tpb, 0, stream>>>(a, b0, gamma0, beta0, mean0, var0, act, 1, n);

  // ---- layer 1: conv -> BN (no activation)
  k_gemm<<<(n + 31) / 32, tpb, 0, stream>>>(a, W1, h, n);
  k_selfinit<<<(n * (D / 4) + tpb - 1) / tpb, tpb, 0, stream>>>(h, dinv, out, n);
  k_edge_agg<<<(e * 32 + tpb - 1) / tpb, tpb, 0, stream>>>(srcp, dstp, c, h, out, e * 32);
  k_post<<<(n * D + tpb - 1) / tpb, tpb, 0, stream>>>(out, b1, gamma1, beta1, mean1, var1, act, 0, n);
}

// Round 2
// 478.835 us; speedup vs baseline: 4.7365x; 4.7365x over previous
//
#include <hip/hip_runtime.h>
#include <math.h>

#define D 128
#define BN_EPS 1e-5f

// ---------------------------------------------------------------- degree + count
__global__ void k_deg_init(float* deg, int* cnt, int n) {
  int i = blockIdx.x * blockDim.x + threadIdx.x;
  if (i < n) { deg[i] = 1.0f; cnt[i] = 0; }  // self-loop weight 1
}

__global__ void k_deg_cnt(const int* __restrict__ dst, const float* __restrict__ ew,
                          float* deg, int* cnt, int e) {
  int i = blockIdx.x * blockDim.x + threadIdx.x;
  if (i < e) {
    int d = dst[i];
    atomicAdd(&deg[d], ew[i]);
    atomicAdd(&cnt[d], 1);
  }
}

__global__ void k_dinv(float* deg, int n) {
  int i = blockIdx.x * blockDim.x + threadIdx.x;
  if (i < n) {
    float d = deg[i];
    deg[i] = d > 0.f ? rsqrtf(fmaxf(d, 1e-30f)) : 0.f;  // in place -> dinv
  }
}

// ---------------------------------------------------------------- exclusive scan
// Single workgroup of 1024 threads, sequential chunks with carry. 50K elems -> ~us.
__global__ __launch_bounds__(1024) void k_scan_excl(int* cnt, int n) {
  __shared__ int s[1024];
  const int tid = threadIdx.x;
  int carry = 0;
  for (int base = 0; base < n; base += 1024) {
    int i = base + tid;
    int v = (i < n) ? cnt[i] : 0;
    s[tid] = v;
    __syncthreads();
    for (int off = 1; off < 1024; off <<= 1) {
      int t = (tid >= off) ? s[tid - off] : 0;
      __syncthreads();
      s[tid] += t;
      __syncthreads();
    }
    if (i < n) cnt[i] = carry + s[tid] - v;  // exclusive
    int chunk_total = s[1023];
    __syncthreads();  // protect s[] before next chunk overwrites
    carry += chunk_total;
  }
  if (tid == 0) cnt[n] = carry;  // off[n] = e
}

__global__ void k_copy_i(const int* __restrict__ a, int* __restrict__ b, int n) {
  int i = blockIdx.x * blockDim.x + threadIdx.x;
  if (i < n) b[i] = a[i];
}

// ---------------------------------------------------------------- bucket scatter
__global__ void k_bucket(const int* __restrict__ src, const int* __restrict__ dst,
                         const float* __restrict__ ew, const float* __restrict__ dinv,
                         int* cursor, int* __restrict__ bsrc, float* __restrict__ bcoef,
                         int e) {
  int i = blockIdx.x * blockDim.x + threadIdx.x;
  if (i < e) {
    int s = src[i], d = dst[i];
    int pos = atomicAdd(&cursor[d], 1);
    bsrc[pos] = s;
    bcoef[pos] = dinv[s] * ew[i] * dinv[d];
  }
}

// ---------------------------------------------------------------- GEMM h = X @ W
// X: [n,128], W: [128,128] row-major. 256 threads -> 32 rows x 128 cols.
__global__ __launch_bounds__(256) void k_gemm(const float* __restrict__ X,
                                              const float* __restrict__ W,
                                              float* __restrict__ H, int n) {
  __shared__ float sW[64][D];   // 32 KB (one k-half)
  __shared__ float sX[32][D];   // 16 KB
  const int tid  = threadIdx.x;
  const int col  = tid & 127;
  const int ty   = tid >> 7;    // 0 or 1
  const int row0 = blockIdx.x * 32;

  for (int i = tid; i < 32 * D; i += 256) {
    int r = i >> 7;
    sX[r][i & 127] = (row0 + r < n) ? X[(size_t)(row0 + r) * D + (i & 127)] : 0.f;
  }

  float acc[16];
#pragma unroll
  for (int t = 0; t < 16; ++t) acc[t] = 0.f;

  for (int ph = 0; ph < 2; ++ph) {
    __syncthreads();
    for (int i = tid; i < 64 * D; i += 256)
      sW[i >> 7][i & 127] = W[(size_t)(ph * 64 + (i >> 7)) * D + (i & 127)];
    __syncthreads();
#pragma unroll 1
    for (int k = 0; k < 64; ++k) {
      float w = sW[k][col];
#pragma unroll
      for (int t = 0; t < 16; ++t)
        acc[t] += sX[2 * t + ty][ph * 64 + k] * w;
    }
  }
#pragma unroll
  for (int t = 0; t < 16; ++t) {
    int r = row0 + 2 * t + ty;
    if (r < n) H[(size_t)r * D + col] = acc[t];
  }
}

// ------------------------------------------------- fused aggregation + bias + BN (+act)
// One 32-lane group per dst node: self-loop + CSR in-edges, registers only, one store.
__global__ __launch_bounds__(256) void k_agg(const float* __restrict__ H,
                                             const int* __restrict__ off,
                                             const int* __restrict__ bsrc,
                                             const float* __restrict__ bcoef,
                                             const float* __restrict__ dinv,
                                             const float* __restrict__ bias,
                                             const float* __restrict__ gamma,
                                             const float* __restrict__ beta,
                                             const float* __restrict__ mean,
                                             const float* __restrict__ var,
                                             const float* __restrict__ act_params,
                                             int with_act, float* __restrict__ out, int n) {
  int g = blockIdx.x * 8 + (threadIdx.x >> 5);
  if (g >= n) return;
  const int lane = threadIdx.x & 31;
  const int j = lane * 4;

  float di = dinv[g];
  float self = di * di;
  float4 v = *(const float4*)(H + (size_t)g * D + j);
  float4 acc = { v.x * self, v.y * self, v.z * self, v.w * self };

  int k0 = off[g], k1 = off[g + 1];
  for (int k = k0; k < k1; ++k) {
    int s = bsrc[k];
    float cf = bcoef[k];
    float4 u = *(const float4*)(H + (size_t)s * D + j);
    acc.x += cf * u.x; acc.y += cf * u.y; acc.z += cf * u.z; acc.w += cf * u.w;
  }

  float4 bb = *(const float4*)(bias + j);
  float4 gm = *(const float4*)(gamma + j);
  float4 bt = *(const float4*)(beta + j);
  float4 mn = *(const float4*)(mean + j);
  float4 vr = *(const float4*)(var + j);

  float r[4] = { acc.x + bb.x, acc.y + bb.y, acc.z + bb.z, acc.w + bb.w };
  float gmv[4] = { gm.x, gm.y, gm.z, gm.w };
  float btv[4] = { bt.x, bt.y, bt.z, bt.w };
  float mnv[4] = { mn.x, mn.y, mn.z, mn.w };
  float vrv[4] = { vr.x, vr.y, vr.z, vr.w };

  float alpha = with_act ? 1.f / (1.f + expf(-act_params[0])) : 0.f;

#pragma unroll
  for (int t = 0; t < 4; ++t) {
    float vv = (r[t] - mnv[t]) * rsqrtf(vrv[t] + BN_EPS) * gmv[t] + btv[t];
    if (with_act) {
      float rl = fmaxf(vv, 0.f);
      float ge = 0.5f * vv * (1.f + erff(vv * 0.70710678118654752f));
      vv = alpha * rl + (1.f - alpha) * ge;
    }
    r[t] = vv;
  }
  float4 res = { r[0], r[1], r[2], r[3] };
  *(float4*)(out + (size_t)g * D + j) = res;
}

// ---------------------------------------------------------------- launch
extern "C" void kernel_launch(void* const* d_in, const int* in_sizes, int n_in,
                              void* d_out, int out_size, void* d_ws, size_t ws_size,
                              hipStream_t stream) {
  const float* x      = (const float*)d_in[0];
  const int*   ei     = (const int*)d_in[1];
  const float* ew     = (const float*)d_in[2];
  const float* W0     = (const float*)d_in[3];
  const float* b0     = (const float*)d_in[4];
  const float* W1     = (const float*)d_in[5];
  const float* b1     = (const float*)d_in[6];
  const float* gamma0 = (const float*)d_in[7];
  const float* beta0  = (const float*)d_in[8];
  const float* mean0  = (const float*)d_in[9];
  const float* var0   = (const float*)d_in[10];
  const float* gamma1 = (const float*)d_in[11];
  const float* beta1  = (const float*)d_in[12];
  const float* mean1  = (const float*)d_in[13];
  const float* var1   = (const float*)d_in[14];
  const float* act    = (const float*)d_in[15];

  const int n = in_sizes[0] / D;
  const int e = in_sizes[2];
  const int* srcp = ei;
  const int* dstp = ei + e;

  // workspace layout
  char* p = (char*)d_ws;
  float* dinv  = (float*)p;            p += sizeof(float) * n;
  int*   off   = (int*)p;              p += sizeof(int) * (n + 1);
  int*   cursor= (int*)p;              p += sizeof(int) * n;
  int*   bsrc  = (int*)p;              p += sizeof(int) * e;
  float* bcoef = (float*)p;            p += sizeof(float) * e;
  float* h     = (float*)p;            p += sizeof(float) * (size_t)n * D;
  float* a     = (float*)p;            p += sizeof(float) * (size_t)n * D;
  float* out   = (float*)d_out;

  const int tpb = 256;
  const int nb_n = (n + tpb - 1) / tpb;
  const int nb_e = (e + tpb - 1) / tpb;

  // degree + in-count -> dinv -> CSR buckets with fused norm coefficient
  k_deg_init<<<nb_n, tpb, 0, stream>>>(dinv, off, n);
  k_deg_cnt<<<nb_e, tpb, 0, stream>>>(dstp, ew, dinv, off, e);
  k_dinv<<<nb_n, tpb, 0, stream>>>(dinv, n);
  k_scan_excl<<<1, 1024, 0, stream>>>(off, n);
  k_copy_i<<<nb_n, tpb, 0, stream>>>(off, cursor, n);
  k_bucket<<<nb_e, tpb, 0, stream>>>(srcp, dstp, ew, dinv, cursor, bsrc, bcoef, e);

  // ---- layer 0: conv -> agg (+bias+BN+blended activation fused)
  k_gemm<<<(n + 31) / 32, tpb, 0, stream>>>(x, W0, h, n);
  k_agg<<<(n + 7) / 8, tpb, 0, stream>>>(h, off, bsrc, bcoef, dinv, b0,
                                         gamma0, beta0, mean0, var0, act, 1, a, n);

  // ---- layer 1: conv -> agg (+bias+BN fused, no activation)
  k_gemm<<<(n + 31) / 32, tpb, 0, stream>>>(a, W1, h, n);
  k_agg<<<(n + 7) / 8, tpb, 0, stream>>>(h, off, bsrc, bcoef, dinv, b1,
                                         gamma1, beta1, mean1, var1, act, 0, out, n);
}

// Round 3
// 299.675 us; speedup vs baseline: 7.5681x; 1.5978x over previous
//
#include <hip/hip_runtime.h>
#include <math.h>

#define D 128
#define BN_EPS 1e-5f

// ---------------------------------------------------------------- degree + count
__global__ void k_deg_init(float* deg, int* cnt, int n) {
  int i = blockIdx.x * blockDim.x + threadIdx.x;
  if (i < n) { deg[i] = 1.0f; cnt[i] = 0; }  // self-loop weight 1
}

__global__ void k_deg_cnt(const int* __restrict__ dst, const float* __restrict__ ew,
                          float* deg, int* cnt, int e) {
  int i = blockIdx.x * blockDim.x + threadIdx.x;
  if (i < e) {
    int d = dst[i];
    atomicAdd(&deg[d], ew[i]);
    atomicAdd(&cnt[d], 1);
  }
}

__global__ void k_dinv(float* deg, int n) {
  int i = blockIdx.x * blockDim.x + threadIdx.x;
  if (i < n) {
    float d = deg[i];
    deg[i] = d > 0.f ? rsqrtf(fmaxf(d, 1e-30f)) : 0.f;  // in place -> dinv
  }
}

// ---------------------------------------------------------------- parallel scan
// Phase 1: per-block (1024) exclusive scan via wave shuffles; block sums out.
__global__ __launch_bounds__(1024) void k_scan1(int* data, int* bsum, int n) {
  __shared__ int ws[16];
  const int tid = threadIdx.x;
  const int i = blockIdx.x * 1024 + tid;
  int v = (i < n) ? data[i] : 0;
  int x = v;
#pragma unroll
  for (int d = 1; d < 64; d <<= 1) {
    int y = __shfl_up(x, d, 64);
    if ((tid & 63) >= d) x += y;
  }
  const int wid = tid >> 6;
  if ((tid & 63) == 63) ws[wid] = x;
  __syncthreads();
  if (wid == 0) {
    int s = (tid < 16) ? ws[tid] : 0;
#pragma unroll
    for (int d = 1; d < 16; d <<= 1) {
      int y = __shfl_up(s, d, 64);
      if (tid >= d && tid < 16) s += y;
    }
    if (tid < 16) ws[tid] = s;  // inclusive wave sums
  }
  __syncthreads();
  int woff = (wid > 0) ? ws[wid - 1] : 0;
  if (i < n) data[i] = woff + x - v;  // exclusive within block
  if (tid == 1023) bsum[blockIdx.x] = ws[15];
}

// Phase 2: single block scans block sums (nb <= 1024), writes grand total.
__global__ __launch_bounds__(1024) void k_scan2(int* bsum, int nb, int* total_loc) {
  __shared__ int ws[16];
  const int tid = threadIdx.x;
  int v = (tid < nb) ? bsum[tid] : 0;
  int x = v;
#pragma unroll
  for (int d = 1; d < 64; d <<= 1) {
    int y = __shfl_up(x, d, 64);
    if ((tid & 63) >= d) x += y;
  }
  const int wid = tid >> 6;
  if ((tid & 63) == 63) ws[wid] = x;
  __syncthreads();
  if (wid == 0) {
    int s = (tid < 16) ? ws[tid] : 0;
#pragma unroll
    for (int d = 1; d < 16; d <<= 1) {
      int y = __shfl_up(s, d, 64);
      if (tid >= d && tid < 16) s += y;
    }
    if (tid < 16) ws[tid] = s;
  }
  __syncthreads();
  int woff = (wid > 0) ? ws[wid - 1] : 0;
  if (tid < nb) bsum[tid] = woff + x - v;
  if (tid == 1023) *total_loc = ws[15];
}

// Phase 3: add block offsets; also produce cursor copy for bucket scatter.
__global__ __launch_bounds__(1024) void k_scan3(int* off, const int* __restrict__ bsum,
                                                int* cursor, int n) {
  const int i = blockIdx.x * 1024 + threadIdx.x;
  if (i < n) {
    int v = off[i] + bsum[blockIdx.x];
    off[i] = v;
    cursor[i] = v;
  }
}

// ---------------------------------------------------------------- bucket scatter
__global__ void k_bucket(const int* __restrict__ src, const int* __restrict__ dst,
                         const float* __restrict__ ew, const float* __restrict__ dinv,
                         int* cursor, int* __restrict__ bsrc, float* __restrict__ bcoef,
                         int e) {
  int i = blockIdx.x * blockDim.x + threadIdx.x;
  if (i < e) {
    int s = src[i], d = dst[i];
    int pos = atomicAdd(&cursor[d], 1);
    bsrc[pos] = s;
    bcoef[pos] = dinv[s] * ew[i] * dinv[d];
  }
}

// ---------------------------------------------------------------- GEMM H = X @ W
// BM=64 rows x BN=128 cols per block, BK=64 x 2 phases. 256 threads, each owns
// an 8x4 register tile. Per k-step: 3x ds_read_b128 (36cyc) vs 32 FMA (64cyc).
__global__ __launch_bounds__(256) void k_gemm(const float* __restrict__ X,
                                              const float* __restrict__ W,
                                              float* __restrict__ H, int n) {
  __shared__ float sXt[64][68];   // transposed X tile, padded for 16B-aligned rows
  __shared__ float sW[64][128];
  const int tid = threadIdx.x;
  const int tc = tid & 31;        // col group: cols 4*tc..4*tc+3
  const int tr = tid >> 5;        // row group: rows 8*tr..8*tr+7
  const int row0 = blockIdx.x * 64;

  float acc[8][4];
#pragma unroll
  for (int m = 0; m < 8; ++m)
#pragma unroll
    for (int c = 0; c < 4; ++c) acc[m][c] = 0.f;

  for (int ph = 0; ph < 2; ++ph) {
    __syncthreads();  // previous phase's LDS consumed
    // stage X^T: 64 rows x 64 k (16 float4 per row)
    for (int i = tid; i < 64 * 16; i += 256) {
      int r = i >> 4, c4 = (i & 15) * 4;
      float4 v = (row0 + r < n)
          ? *(const float4*)(X + (size_t)(row0 + r) * D + ph * 64 + c4)
          : make_float4(0.f, 0.f, 0.f, 0.f);
      sXt[c4 + 0][r] = v.x; sXt[c4 + 1][r] = v.y;
      sXt[c4 + 2][r] = v.z; sXt[c4 + 3][r] = v.w;
    }
    // stage W: 64 k-rows x 128 cols
    for (int i = tid; i < 64 * 32; i += 256) {
      int r = i >> 5, c4 = (i & 31) * 4;
      *(float4*)&sW[r][c4] = *(const float4*)(W + (size_t)(ph * 64 + r) * D + c4);
    }
    __syncthreads();

#pragma unroll 2
    for (int kk = 0; kk < 64; ++kk) {
      float4 a0 = *(const float4*)&sXt[kk][tr * 8];
      float4 a1 = *(const float4*)&sXt[kk][tr * 8 + 4];
      float4 b = *(const float4*)&sW[kk][tc * 4];
      float av[8] = { a0.x, a0.y, a0.z, a0.w, a1.x, a1.y, a1.z, a1.w };
      float bv[4] = { b.x, b.y, b.z, b.w };
#pragma unroll
      for (int m = 0; m < 8; ++m)
#pragma unroll
        for (int c = 0; c < 4; ++c) acc[m][c] += av[m] * bv[c];
    }
  }

#pragma unroll
  for (int m = 0; m < 8; ++m) {
    int r = row0 + tr * 8 + m;
    if (r < n) {
      float4 res = { acc[m][0], acc[m][1], acc[m][2], acc[m][3] };
      *(float4*)(H + (size_t)r * D + tc * 4) = res;
    }
  }
}

// ------------------------------------------------- fused aggregation + bias + BN (+act)
// One 32-lane group per dst node: self-loop + CSR in-edges, registers only, one store.
__global__ __launch_bounds__(256) void k_agg(const float* __restrict__ H,
                                             const int* __restrict__ off,
                                             const int* __restrict__ bsrc,
                                             const float* __restrict__ bcoef,
                                             const float* __restrict__ dinv,
                                             const float* __restrict__ bias,
                                             const float* __restrict__ gamma,
                                             const float* __restrict__ beta,
                                             const float* __restrict__ mean,
                                             const float* __restrict__ var,
                                             const float* __restrict__ act_params,
                                             int with_act, float* __restrict__ out, int n) {
  int g = blockIdx.x * 8 + (threadIdx.x >> 5);
  if (g >= n) return;
  const int j = (threadIdx.x & 31) * 4;

  float di = dinv[g];
  float self = di * di;
  float4 v = *(const float4*)(H + (size_t)g * D + j);
  float4 acc = { v.x * self, v.y * self, v.z * self, v.w * self };

  int k = off[g], k1 = off[g + 1];
  for (; k + 1 < k1; k += 2) {  // 2 independent gathers in flight
    int s0 = bsrc[k], s1 = bsrc[k + 1];
    float c0 = bcoef[k], c1 = bcoef[k + 1];
    float4 u0 = *(const float4*)(H + (size_t)s0 * D + j);
    float4 u1 = *(const float4*)(H + (size_t)s1 * D + j);
    acc.x += c0 * u0.x + c1 * u1.x;
    acc.y += c0 * u0.y + c1 * u1.y;
    acc.z += c0 * u0.z + c1 * u1.z;
    acc.w += c0 * u0.w + c1 * u1.w;
  }
  if (k < k1) {
    int s = bsrc[k];
    float cf = bcoef[k];
    float4 u = *(const float4*)(H + (size_t)s * D + j);
    acc.x += cf * u.x; acc.y += cf * u.y; acc.z += cf * u.z; acc.w += cf * u.w;
  }

  float4 bb = *(const float4*)(bias + j);
  float4 gm = *(const float4*)(gamma + j);
  float4 bt = *(const float4*)(beta + j);
  float4 mn = *(const float4*)(mean + j);
  float4 vr = *(const float4*)(var + j);

  float r[4] = { acc.x + bb.x, acc.y + bb.y, acc.z + bb.z, acc.w + bb.w };
  float gmv[4] = { gm.x, gm.y, gm.z, gm.w };
  float btv[4] = { bt.x, bt.y, bt.z, bt.w };
  float mnv[4] = { mn.x, mn.y, mn.z, mn.w };
  float vrv[4] = { vr.x, vr.y, vr.z, vr.w };

  float alpha = with_act ? 1.f / (1.f + expf(-act_params[0])) : 0.f;

#pragma unroll
  for (int t = 0; t < 4; ++t) {
    float vv = (r[t] - mnv[t]) * rsqrtf(vrv[t] + BN_EPS) * gmv[t] + btv[t];
    if (with_act) {
      float rl = fmaxf(vv, 0.f);
      float ge = 0.5f * vv * (1.f + erff(vv * 0.70710678118654752f));
      vv = alpha * rl + (1.f - alpha) * ge;
    }
    r[t] = vv;
  }
  float4 res = { r[0], r[1], r[2], r[3] };
  *(float4*)(out + (size_t)g * D + j) = res;
}

// ---------------------------------------------------------------- launch
extern "C" void kernel_launch(void* const* d_in, const int* in_sizes, int n_in,
                              void* d_out, int out_size, void* d_ws, size_t ws_size,
                              hipStream_t stream) {
  const float* x      = (const float*)d_in[0];
  const int*   ei     = (const int*)d_in[1];
  const float* ew     = (const float*)d_in[2];
  const float* W0     = (const float*)d_in[3];
  const float* b0     = (const float*)d_in[4];
  const float* W1     = (const float*)d_in[5];
  const float* b1     = (const float*)d_in[6];
  const float* gamma0 = (const float*)d_in[7];
  const float* beta0  = (const float*)d_in[8];
  const float* mean0  = (const float*)d_in[9];
  const float* var0   = (const float*)d_in[10];
  const float* gamma1 = (const float*)d_in[11];
  const float* beta1  = (const float*)d_in[12];
  const float* mean1  = (const float*)d_in[13];
  const float* var1   = (const float*)d_in[14];
  const float* act    = (const float*)d_in[15];

  const int n = in_sizes[0] / D;
  const int e = in_sizes[2];
  const int* srcp = ei;
  const int* dstp = ei + e;

  // workspace layout
  char* p = (char*)d_ws;
  float* dinv  = (float*)p;            p += sizeof(float) * n;
  int*   off   = (int*)p;              p += sizeof(int) * (n + 1);
  int*   cursor= (int*)p;              p += sizeof(int) * n;
  int*   bsum  = (int*)p;              p += sizeof(int) * 1024;
  int*   bsrc  = (int*)p;              p += sizeof(int) * e;
  float* bcoef = (float*)p;            p += sizeof(float) * e;
  float* h     = (float*)p;            p += sizeof(float) * (size_t)n * D;
  float* a     = (float*)p;            p += sizeof(float) * (size_t)n * D;
  float* out   = (float*)d_out;

  const int tpb = 256;
  const int nb_n = (n + tpb - 1) / tpb;
  const int nb_e = (e + tpb - 1) / tpb;
  const int nb_s = (n + 1023) / 1024;  // scan blocks (49 for n=50000)

  // degree + in-count -> dinv -> parallel scan -> CSR buckets with fused coef
  k_deg_init<<<nb_n, tpb, 0, stream>>>(dinv, off, n);
  k_deg_cnt<<<nb_e, tpb, 0, stream>>>(dstp, ew, dinv, off, e);
  k_dinv<<<nb_n, tpb, 0, stream>>>(dinv, n);
  k_scan1<<<nb_s, 1024, 0, stream>>>(off, bsum, n);
  k_scan2<<<1, 1024, 0, stream>>>(bsum, nb_s, off + n);
  k_scan3<<<nb_s, 1024, 0, stream>>>(off, bsum, cursor, n);
  k_bucket<<<nb_e, tpb, 0, stream>>>(srcp, dstp, ew, dinv, cursor, bsrc, bcoef, e);

  // ---- layer 0: conv -> agg (+bias+BN+blended activation fused)
  k_gemm<<<(n + 63) / 64, tpb, 0, stream>>>(x, W0, h, n);
  k_agg<<<(n + 7) / 8, tpb, 0, stream>>>(h, off, bsrc, bcoef, dinv, b0,
                                         gamma0, beta0, mean0, var0, act, 1, a, n);

  // ---- layer 1: conv -> agg (+bias+BN fused, no activation)
  k_gemm<<<(n + 63) / 64, tpb, 0, stream>>>(a, W1, h, n);
  k_agg<<<(n + 7) / 8, tpb, 0, stream>>>(h, off, bsrc, bcoef, dinv, b1,
                                         gamma1, beta1, mean1, var1, act, 0, out, n);
}

// Round 4
// 226.738 us; speedup vs baseline: 10.0026x; 1.3217x over previous
//
#include <hip/hip_runtime.h>
#include <hip/hip_fp16.h>
#include <math.h>

#define D 128
#define BN_EPS 1e-5f

// ---------------------------------------------------------------- init counts
__global__ void k_init(int* cnt, int n1) {
  int i = blockIdx.x * blockDim.x + threadIdx.x;
  if (i < n1) cnt[i] = 0;
}

// ---------------------------------------------------------------- in-degree count
__global__ void k_cnt(const int* __restrict__ dst, int* cnt, int e) {
  int i = blockIdx.x * blockDim.x + threadIdx.x;
  if (i < e) atomicAdd(&cnt[dst[i]], 1);
}

// ---------------------------------------------------------------- parallel scan
__global__ __launch_bounds__(1024) void k_scan1(int* data, int* bsum, int n) {
  __shared__ int ws[16];
  const int tid = threadIdx.x;
  const int i = blockIdx.x * 1024 + tid;
  int v = (i < n) ? data[i] : 0;
  int x = v;
#pragma unroll
  for (int d = 1; d < 64; d <<= 1) {
    int y = __shfl_up(x, d, 64);
    if ((tid & 63) >= d) x += y;
  }
  const int wid = tid >> 6;
  if ((tid & 63) == 63) ws[wid] = x;
  __syncthreads();
  if (wid == 0) {
    int s = (tid < 16) ? ws[tid] : 0;
#pragma unroll
    for (int d = 1; d < 16; d <<= 1) {
      int y = __shfl_up(s, d, 64);
      if (tid >= d && tid < 16) s += y;
    }
    if (tid < 16) ws[tid] = s;
  }
  __syncthreads();
  int woff = (wid > 0) ? ws[wid - 1] : 0;
  if (i < n) data[i] = woff + x - v;  // exclusive within block
  if (tid == 1023) bsum[blockIdx.x] = ws[15];
}

__global__ __launch_bounds__(1024) void k_scan2(int* bsum, int nb, int* total_loc) {
  __shared__ int ws[16];
  const int tid = threadIdx.x;
  int v = (tid < nb) ? bsum[tid] : 0;
  int x = v;
#pragma unroll
  for (int d = 1; d < 64; d <<= 1) {
    int y = __shfl_up(x, d, 64);
    if ((tid & 63) >= d) x += y;
  }
  const int wid = tid >> 6;
  if ((tid & 63) == 63) ws[wid] = x;
  __syncthreads();
  if (wid == 0) {
    int s = (tid < 16) ? ws[tid] : 0;
#pragma unroll
    for (int d = 1; d < 16; d <<= 1) {
      int y = __shfl_up(s, d, 64);
      if (tid >= d && tid < 16) s += y;
    }
    if (tid < 16) ws[tid] = s;
  }
  __syncthreads();
  int woff = (wid > 0) ? ws[wid - 1] : 0;
  if (tid < nb) bsum[tid] = woff + x - v;
  if (tid == 1023) *total_loc = ws[15];
}

__global__ __launch_bounds__(1024) void k_scan3(int* off, const int* __restrict__ bsum,
                                                int* cursor, int n) {
  const int i = blockIdx.x * 1024 + threadIdx.x;
  if (i < n) {
    int v = off[i] + bsum[blockIdx.x];
    off[i] = v;
    cursor[i] = v;
  }
}

// ---------------------------------------------------------------- bucket scatter
// pack = {src, bits(ew)} -- one 8B store; norm coef computed later in k_agg.
__global__ void k_bucket(const int* __restrict__ src, const int* __restrict__ dst,
                         const float* __restrict__ ew, int* cursor,
                         uint2* __restrict__ pack, int e) {
  int i = blockIdx.x * blockDim.x + threadIdx.x;
  if (i < e) {
    int d = dst[i];
    int pos = atomicAdd(&cursor[d], 1);
    pack[pos] = make_uint2((unsigned)src[i], __float_as_uint(ew[i]));
  }
}

// ---------------------------------------------------------------- degree -> dinv
// Thread per node: bucket is contiguous, stream it.
__global__ void k_degdinv(const int* __restrict__ off, const uint2* __restrict__ pack,
                          float* __restrict__ dinv, int n) {
  int g = blockIdx.x * blockDim.x + threadIdx.x;
  if (g < n) {
    float deg = 1.0f;  // self-loop weight
    int k1 = off[g + 1];
    for (int k = off[g]; k < k1; ++k) deg += __uint_as_float(pack[k].y);
    dinv[g] = rsqrtf(deg);
  }
}

// ---------------------------------------------------------------- GEMM H16 = X @ W
// BM=64 x BN=128, BK=64 x 2 phases, 256 threads, 8x4 register tile. fp16 output.
__global__ __launch_bounds__(256) void k_gemm(const float* __restrict__ X,
                                              const float* __restrict__ W,
                                              __half* __restrict__ H, int n) {
  __shared__ float sXt[64][68];
  __shared__ float sW[64][128];
  const int tid = threadIdx.x;
  const int tc = tid & 31;
  const int tr = tid >> 5;
  const int row0 = blockIdx.x * 64;

  float acc[8][4];
#pragma unroll
  for (int m = 0; m < 8; ++m)
#pragma unroll
    for (int c = 0; c < 4; ++c) acc[m][c] = 0.f;

  for (int ph = 0; ph < 2; ++ph) {
    __syncthreads();
    for (int i = tid; i < 64 * 16; i += 256) {
      int r = i >> 4, c4 = (i & 15) * 4;
      float4 v = (row0 + r < n)
          ? *(const float4*)(X + (size_t)(row0 + r) * D + ph * 64 + c4)
          : make_float4(0.f, 0.f, 0.f, 0.f);
      sXt[c4 + 0][r] = v.x; sXt[c4 + 1][r] = v.y;
      sXt[c4 + 2][r] = v.z; sXt[c4 + 3][r] = v.w;
    }
    for (int i = tid; i < 64 * 32; i += 256) {
      int r = i >> 5, c4 = (i & 31) * 4;
      *(float4*)&sW[r][c4] = *(const float4*)(W + (size_t)(ph * 64 + r) * D + c4);
    }
    __syncthreads();

#pragma unroll 2
    for (int kk = 0; kk < 64; ++kk) {
      float4 a0 = *(const float4*)&sXt[kk][tr * 8];
      float4 a1 = *(const float4*)&sXt[kk][tr * 8 + 4];
      float4 b = *(const float4*)&sW[kk][tc * 4];
      float av[8] = { a0.x, a0.y, a0.z, a0.w, a1.x, a1.y, a1.z, a1.w };
      float bv[4] = { b.x, b.y, b.z, b.w };
#pragma unroll
      for (int m = 0; m < 8; ++m)
#pragma unroll
        for (int c = 0; c < 4; ++c) acc[m][c] += av[m] * bv[c];
    }
  }

#pragma unroll
  for (int m = 0; m < 8; ++m) {
    int r = row0 + tr * 8 + m;
    if (r < n) {
      __half2 p0 = __floats2half2_rn(acc[m][0], acc[m][1]);
      __half2 p1 = __floats2half2_rn(acc[m][2], acc[m][3]);
      uint2 st;
      st.x = *(unsigned int*)&p0;
      st.y = *(unsigned int*)&p1;
      *(uint2*)(H + (size_t)r * D + tc * 4) = st;
    }
  }
}

// ------------------------------------------------- fused agg + bias + BN (+act)
// 16-lane group per dst node; lane owns 8 features (16B fp16 load).
// acc = dinv[g] * sum_k (dinv[s]*ew) * H[s]  +  dinv[g]^2 * H[g]
__device__ __forceinline__ void h8_to_f(const uint4& r, float* f) {
  const __half2* hp = (const __half2*)&r;
#pragma unroll
  for (int t = 0; t < 4; ++t) {
    float2 v = __half22float2(hp[t]);
    f[2 * t] = v.x; f[2 * t + 1] = v.y;
  }
}

__global__ __launch_bounds__(256) void k_agg(const __half* __restrict__ H,
                                             const int* __restrict__ off,
                                             const uint2* __restrict__ pack,
                                             const float* __restrict__ dinv,
                                             const float* __restrict__ bias,
                                             const float* __restrict__ gamma,
                                             const float* __restrict__ beta,
                                             const float* __restrict__ mean,
                                             const float* __restrict__ var,
                                             const float* __restrict__ act_params,
                                             int with_act, float* __restrict__ out, int n) {
  int g = blockIdx.x * 16 + (threadIdx.x >> 4);
  if (g >= n) return;
  const int j = (threadIdx.x & 15) * 8;  // 8 features per lane

  float acc[8];
#pragma unroll
  for (int t = 0; t < 8; ++t) acc[t] = 0.f;

  int k = off[g], k1 = off[g + 1];
  for (; k + 1 < k1; k += 2) {
    uint2 p0 = pack[k], p1 = pack[k + 1];
    float w0 = dinv[p0.x] * __uint_as_float(p0.y);
    float w1 = dinv[p1.x] * __uint_as_float(p1.y);
    uint4 r0 = *(const uint4*)(H + (size_t)p0.x * D + j);
    uint4 r1 = *(const uint4*)(H + (size_t)p1.x * D + j);
    float f0[8], f1[8];
    h8_to_f(r0, f0); h8_to_f(r1, f1);
#pragma unroll
    for (int t = 0; t < 8; ++t) acc[t] += w0 * f0[t] + w1 * f1[t];
  }
  if (k < k1) {
    uint2 p = pack[k];
    float w = dinv[p.x] * __uint_as_float(p.y);
    uint4 r = *(const uint4*)(H + (size_t)p.x * D + j);
    float f[8];
    h8_to_f(r, f);
#pragma unroll
    for (int t = 0; t < 8; ++t) acc[t] += w * f[t];
  }

  float dg = dinv[g];
  uint4 rs = *(const uint4*)(H + (size_t)g * D + j);
  float fs[8];
  h8_to_f(rs, fs);
#pragma unroll
  for (int t = 0; t < 8; ++t) acc[t] = dg * acc[t] + dg * dg * fs[t];

  float bb[8], gm[8], bt[8], mn[8], vr[8];
  *(float4*)&bb[0] = *(const float4*)(bias + j);  *(float4*)&bb[4] = *(const float4*)(bias + j + 4);
  *(float4*)&gm[0] = *(const float4*)(gamma + j); *(float4*)&gm[4] = *(const float4*)(gamma + j + 4);
  *(float4*)&bt[0] = *(const float4*)(beta + j);  *(float4*)&bt[4] = *(const float4*)(beta + j + 4);
  *(float4*)&mn[0] = *(const float4*)(mean + j);  *(float4*)&mn[4] = *(const float4*)(mean + j + 4);
  *(float4*)&vr[0] = *(const float4*)(var + j);   *(float4*)&vr[4] = *(const float4*)(var + j + 4);

  float alpha = with_act ? 1.f / (1.f + expf(-act_params[0])) : 0.f;

#pragma unroll
  for (int t = 0; t < 8; ++t) {
    float vv = (acc[t] + bb[t] - mn[t]) * rsqrtf(vr[t] + BN_EPS) * gm[t] + bt[t];
    if (with_act) {
      float rl = fmaxf(vv, 0.f);
      float ge = 0.5f * vv * (1.f + erff(vv * 0.70710678118654752f));
      vv = alpha * rl + (1.f - alpha) * ge;
    }
    acc[t] = vv;
  }
  *(float4*)(out + (size_t)g * D + j)     = make_float4(acc[0], acc[1], acc[2], acc[3]);
  *(float4*)(out + (size_t)g * D + j + 4) = make_float4(acc[4], acc[5], acc[6], acc[7]);
}

// ---------------------------------------------------------------- launch
extern "C" void kernel_launch(void* const* d_in, const int* in_sizes, int n_in,
                              void* d_out, int out_size, void* d_ws, size_t ws_size,
                              hipStream_t stream) {
  const float* x      = (const float*)d_in[0];
  const int*   ei     = (const int*)d_in[1];
  const float* ew     = (const float*)d_in[2];
  const float* W0     = (const float*)d_in[3];
  const float* b0     = (const float*)d_in[4];
  const float* W1     = (const float*)d_in[5];
  const float* b1     = (const float*)d_in[6];
  const float* gamma0 = (const float*)d_in[7];
  const float* beta0  = (const float*)d_in[8];
  const float* mean0  = (const float*)d_in[9];
  const float* var0   = (const float*)d_in[10];
  const float* gamma1 = (const float*)d_in[11];
  const float* beta1  = (const float*)d_in[12];
  const float* mean1  = (const float*)d_in[13];
  const float* var1   = (const float*)d_in[14];
  const float* act    = (const float*)d_in[15];

  const int n = in_sizes[0] / D;
  const int e = in_sizes[2];
  const int* srcp = ei;
  const int* dstp = ei + e;

  // workspace layout
  char* p = (char*)d_ws;
  float* dinv   = (float*)p;  p += sizeof(float) * n;
  int*   off    = (int*)p;    p += sizeof(int) * (n + 1);
  int*   cursor = (int*)p;    p += sizeof(int) * n;
  int*   bsum   = (int*)p;    p += sizeof(int) * 1024;
  uint2* pack   = (uint2*)p;  p += sizeof(uint2) * e;
  __half* h16   = (__half*)p; p += sizeof(__half) * (size_t)n * D;
  float* a      = (float*)p;  p += sizeof(float) * (size_t)n * D;
  float* out    = (float*)d_out;

  const int tpb = 256;
  const int nb_n = (n + tpb - 1) / tpb;
  const int nb_e = (e + tpb - 1) / tpb;
  const int nb_s = (n + 1023) / 1024;

  k_init<<<(n + 1 + tpb - 1) / tpb, tpb, 0, stream>>>(off, n + 1);
  k_cnt<<<nb_e, tpb, 0, stream>>>(dstp, off, e);
  k_scan1<<<nb_s, 1024, 0, stream>>>(off, bsum, n);
  k_scan2<<<1, 1024, 0, stream>>>(bsum, nb_s, off + n);
  k_scan3<<<nb_s, 1024, 0, stream>>>(off, bsum, cursor, n);
  k_bucket<<<nb_e, tpb, 0, stream>>>(srcp, dstp, ew, cursor, pack, e);
  k_degdinv<<<nb_n, tpb, 0, stream>>>(off, pack, dinv, n);

  // ---- layer 0: conv -> agg (+bias+BN+blended activation fused)
  k_gemm<<<(n + 63) / 64, tpb, 0, stream>>>(x, W0, h16, n);
  k_agg<<<(n + 15) / 16, tpb, 0, stream>>>(h16, off, pack, dinv, b0,
                                           gamma0, beta0, mean0, var0, act, 1, a, n);

  // ---- layer 1: conv -> agg (+bias+BN fused, no activation)
  k_gemm<<<(n + 63) / 64, tpb, 0, stream>>>(a, W1, h16, n);
  k_agg<<<(n + 15) / 16, tpb, 0, stream>>>(h16, off, pack, dinv, b1,
                                           gamma1, beta1, mean1, var1, act, 0, out, n);
}

// Round 5
// 195.918 us; speedup vs baseline: 11.5761x; 1.1573x over previous
//
#include <hip/hip_runtime.h>
#include <hip/hip_fp16.h>
#include <math.h>

#define D 128
#define BN_EPS 1e-5f

// ---------------------------------------------------------------- fused: count+rank || gemm0
// Blocks [0,Gc): rank[i] = atomicAdd(cnt[dst[i]],1)  (cnt pre-zeroed via memset)
// Blocks [Gc,..): GEMM tile (X @ W -> H fp16), BM=64 x BN=128, 8x4 reg tile.
__global__ __launch_bounds__(256) void k_mega0(const float* __restrict__ X,
                                               const float* __restrict__ W,
                                               __half* __restrict__ H,
                                               const int* __restrict__ dst,
                                               int* cnt, int* __restrict__ rank,
                                               int n, int e, int Gc) {
  if ((int)blockIdx.x < Gc) {
    int base = blockIdx.x * 1024 + threadIdx.x;
#pragma unroll
    for (int j = 0; j < 4; ++j) {
      int i = base + j * 256;
      if (i < e) rank[i] = atomicAdd(&cnt[dst[i]], 1);
    }
    return;
  }

  __shared__ float sXt[64][68];
  __shared__ float sW[64][128];
  const int tid = threadIdx.x;
  const int tc = tid & 31;
  const int tr = tid >> 5;
  const int row0 = (blockIdx.x - Gc) * 64;

  float acc[8][4];
#pragma unroll
  for (int m = 0; m < 8; ++m)
#pragma unroll
    for (int c = 0; c < 4; ++c) acc[m][c] = 0.f;

  for (int ph = 0; ph < 2; ++ph) {
    __syncthreads();
    for (int i = tid; i < 64 * 16; i += 256) {
      int r = i >> 4, c4 = (i & 15) * 4;
      float4 v = (row0 + r < n)
          ? *(const float4*)(X + (size_t)(row0 + r) * D + ph * 64 + c4)
          : make_float4(0.f, 0.f, 0.f, 0.f);
      sXt[c4 + 0][r] = v.x; sXt[c4 + 1][r] = v.y;
      sXt[c4 + 2][r] = v.z; sXt[c4 + 3][r] = v.w;
    }
    for (int i = tid; i < 64 * 32; i += 256) {
      int r = i >> 5, c4 = (i & 31) * 4;
      *(float4*)&sW[r][c4] = *(const float4*)(W + (size_t)(ph * 64 + r) * D + c4);
    }
    __syncthreads();

#pragma unroll 2
    for (int kk = 0; kk < 64; ++kk) {
      float4 a0 = *(const float4*)&sXt[kk][tr * 8];
      float4 a1 = *(const float4*)&sXt[kk][tr * 8 + 4];
      float4 b = *(const float4*)&sW[kk][tc * 4];
      float av[8] = { a0.x, a0.y, a0.z, a0.w, a1.x, a1.y, a1.z, a1.w };
      float bv[4] = { b.x, b.y, b.z, b.w };
#pragma unroll
      for (int m = 0; m < 8; ++m)
#pragma unroll
        for (int c = 0; c < 4; ++c) acc[m][c] += av[m] * bv[c];
    }
  }

#pragma unroll
  for (int m = 0; m < 8; ++m) {
    int r = row0 + tr * 8 + m;
    if (r < n) {
      __half2 p0 = __floats2half2_rn(acc[m][0], acc[m][1]);
      __half2 p1 = __floats2half2_rn(acc[m][2], acc[m][3]);
      uint2 st;
      st.x = *(unsigned int*)&p0;
      st.y = *(unsigned int*)&p1;
      *(uint2*)(H + (size_t)r * D + tc * 4) = st;
    }
  }
}

// ---------------------------------------------------------------- plain GEMM (layer 1)
__global__ __launch_bounds__(256) void k_gemm(const float* __restrict__ X,
                                              const float* __restrict__ W,
                                              __half* __restrict__ H, int n) {
  __shared__ float sXt[64][68];
  __shared__ float sW[64][128];
  const int tid = threadIdx.x;
  const int tc = tid & 31;
  const int tr = tid >> 5;
  const int row0 = blockIdx.x * 64;

  float acc[8][4];
#pragma unroll
  for (int m = 0; m < 8; ++m)
#pragma unroll
    for (int c = 0; c < 4; ++c) acc[m][c] = 0.f;

  for (int ph = 0; ph < 2; ++ph) {
    __syncthreads();
    for (int i = tid; i < 64 * 16; i += 256) {
      int r = i >> 4, c4 = (i & 15) * 4;
      float4 v = (row0 + r < n)
          ? *(const float4*)(X + (size_t)(row0 + r) * D + ph * 64 + c4)
          : make_float4(0.f, 0.f, 0.f, 0.f);
      sXt[c4 + 0][r] = v.x; sXt[c4 + 1][r] = v.y;
      sXt[c4 + 2][r] = v.z; sXt[c4 + 3][r] = v.w;
    }
    for (int i = tid; i < 64 * 32; i += 256) {
      int r = i >> 5, c4 = (i & 31) * 4;
      *(float4*)&sW[r][c4] = *(const float4*)(W + (size_t)(ph * 64 + r) * D + c4);
    }
    __syncthreads();

#pragma unroll 2
    for (int kk = 0; kk < 64; ++kk) {
      float4 a0 = *(const float4*)&sXt[kk][tr * 8];
      float4 a1 = *(const float4*)&sXt[kk][tr * 8 + 4];
      float4 b = *(const float4*)&sW[kk][tc * 4];
      float av[8] = { a0.x, a0.y, a0.z, a0.w, a1.x, a1.y, a1.z, a1.w };
      float bv[4] = { b.x, b.y, b.z, b.w };
#pragma unroll
      for (int m = 0; m < 8; ++m)
#pragma unroll
        for (int c = 0; c < 4; ++c) acc[m][c] += av[m] * bv[c];
    }
  }

#pragma unroll
  for (int m = 0; m < 8; ++m) {
    int r = row0 + tr * 8 + m;
    if (r < n) {
      __half2 p0 = __floats2half2_rn(acc[m][0], acc[m][1]);
      __half2 p1 = __floats2half2_rn(acc[m][2], acc[m][3]);
      uint2 st;
      st.x = *(unsigned int*)&p0;
      st.y = *(unsigned int*)&p1;
      *(uint2*)(H + (size_t)r * D + tc * 4) = st;
    }
  }
}

// ---------------------------------------------------------------- parallel scan
__global__ __launch_bounds__(1024) void k_scan1(int* data, int* bsum, int n) {
  __shared__ int ws[16];
  const int tid = threadIdx.x;
  const int i = blockIdx.x * 1024 + tid;
  int v = (i < n) ? data[i] : 0;
  int x = v;
#pragma unroll
  for (int d = 1; d < 64; d <<= 1) {
    int y = __shfl_up(x, d, 64);
    if ((tid & 63) >= d) x += y;
  }
  const int wid = tid >> 6;
  if ((tid & 63) == 63) ws[wid] = x;
  __syncthreads();
  if (wid == 0) {
    int s = (tid < 16) ? ws[tid] : 0;
#pragma unroll
    for (int d = 1; d < 16; d <<= 1) {
      int y = __shfl_up(s, d, 64);
      if (tid >= d && tid < 16) s += y;
    }
    if (tid < 16) ws[tid] = s;
  }
  __syncthreads();
  int woff = (wid > 0) ? ws[wid - 1] : 0;
  if (i < n) data[i] = woff + x - v;  // exclusive within block
  if (tid == 1023) bsum[blockIdx.x] = ws[15];
}

__global__ __launch_bounds__(1024) void k_scan2(int* bsum, int nb, int* total_loc) {
  __shared__ int ws[16];
  const int tid = threadIdx.x;
  int v = (tid < nb) ? bsum[tid] : 0;
  int x = v;
#pragma unroll
  for (int d = 1; d < 64; d <<= 1) {
    int y = __shfl_up(x, d, 64);
    if ((tid & 63) >= d) x += y;
  }
  const int wid = tid >> 6;
  if ((tid & 63) == 63) ws[wid] = x;
  __syncthreads();
  if (wid == 0) {
    int s = (tid < 16) ? ws[tid] : 0;
#pragma unroll
    for (int d = 1; d < 16; d <<= 1) {
      int y = __shfl_up(s, d, 64);
      if (tid >= d && tid < 16) s += y;
    }
    if (tid < 16) ws[tid] = s;
  }
  __syncthreads();
  int woff = (wid > 0) ? ws[wid - 1] : 0;
  if (tid < nb) bsum[tid] = woff + x - v;
  if (tid == 1023) *total_loc = ws[15];
}

__global__ __launch_bounds__(1024) void k_scan3(int* off, const int* __restrict__ bsum, int n) {
  const int i = blockIdx.x * 1024 + threadIdx.x;
  if (i < n) off[i] += bsum[blockIdx.x];
}

// ---------------------------------------------------------------- bucket scatter (NO atomics)
__global__ void k_bucket(const int* __restrict__ src, const int* __restrict__ dst,
                         const float* __restrict__ ew, const int* __restrict__ off,
                         const int* __restrict__ rank, uint2* __restrict__ pack, int e) {
  int i = blockIdx.x * blockDim.x + threadIdx.x;
  if (i < e) {
    int d = dst[i];
    int pos = off[d] + rank[i];
    pack[pos] = make_uint2((unsigned)src[i], __float_as_uint(ew[i]));
  }
}

// ---------------------------------------------------------------- degree -> dinv
__global__ void k_degdinv(const int* __restrict__ off, const uint2* __restrict__ pack,
                          float* __restrict__ dinv, int n) {
  int g = blockIdx.x * blockDim.x + threadIdx.x;
  if (g < n) {
    float deg = 1.0f;  // self-loop weight
    int k1 = off[g + 1];
    for (int k = off[g]; k < k1; ++k) deg += __uint_as_float(pack[k].y);
    dinv[g] = rsqrtf(deg);
  }
}

// ------------------------------------------------- fused agg + bias + BN (+act)
__device__ __forceinline__ void h8_to_f(const uint4& r, float* f) {
  const __half2* hp = (const __half2*)&r;
#pragma unroll
  for (int t = 0; t < 4; ++t) {
    float2 v = __half22float2(hp[t]);
    f[2 * t] = v.x; f[2 * t + 1] = v.y;
  }
}

__global__ __launch_bounds__(256) void k_agg(const __half* __restrict__ H,
                                             const int* __restrict__ off,
                                             const uint2* __restrict__ pack,
                                             const float* __restrict__ dinv,
                                             const float* __restrict__ bias,
                                             const float* __restrict__ gamma,
                                             const float* __restrict__ beta,
                                             const float* __restrict__ mean,
                                             const float* __restrict__ var,
                                             const float* __restrict__ act_params,
                                             int with_act, float* __restrict__ out, int n) {
  int g = blockIdx.x * 16 + (threadIdx.x >> 4);
  if (g >= n) return;
  const int j = (threadIdx.x & 15) * 8;  // 8 features per lane

  float acc[8];
#pragma unroll
  for (int t = 0; t < 8; ++t) acc[t] = 0.f;

  int k = off[g], k1 = off[g + 1];
  for (; k + 1 < k1; k += 2) {
    uint2 p0 = pack[k], p1 = pack[k + 1];
    float w0 = dinv[p0.x] * __uint_as_float(p0.y);
    float w1 = dinv[p1.x] * __uint_as_float(p1.y);
    uint4 r0 = *(const uint4*)(H + (size_t)p0.x * D + j);
    uint4 r1 = *(const uint4*)(H + (size_t)p1.x * D + j);
    float f0[8], f1[8];
    h8_to_f(r0, f0); h8_to_f(r1, f1);
#pragma unroll
    for (int t = 0; t < 8; ++t) acc[t] += w0 * f0[t] + w1 * f1[t];
  }
  if (k < k1) {
    uint2 p = pack[k];
    float w = dinv[p.x] * __uint_as_float(p.y);
    uint4 r = *(const uint4*)(H + (size_t)p.x * D + j);
    float f[8];
    h8_to_f(r, f);
#pragma unroll
    for (int t = 0; t < 8; ++t) acc[t] += w * f[t];
  }

  float dg = dinv[g];
  uint4 rs = *(const uint4*)(H + (size_t)g * D + j);
  float fs[8];
  h8_to_f(rs, fs);
#pragma unroll
  for (int t = 0; t < 8; ++t) acc[t] = dg * acc[t] + dg * dg * fs[t];

  float bb[8], gm[8], bt[8], mn[8], vr[8];
  *(float4*)&bb[0] = *(const float4*)(bias + j);  *(float4*)&bb[4] = *(const float4*)(bias + j + 4);
  *(float4*)&gm[0] = *(const float4*)(gamma + j); *(float4*)&gm[4] = *(const float4*)(gamma + j + 4);
  *(float4*)&bt[0] = *(const float4*)(beta + j);  *(float4*)&bt[4] = *(const float4*)(beta + j + 4);
  *(float4*)&mn[0] = *(const float4*)(mean + j);  *(float4*)&mn[4] = *(const float4*)(mean + j + 4);
  *(float4*)&vr[0] = *(const float4*)(var + j);   *(float4*)&vr[4] = *(const float4*)(var + j + 4);

  float alpha = with_act ? 1.f / (1.f + expf(-act_params[0])) : 0.f;

#pragma unroll
  for (int t = 0; t < 8; ++t) {
    float vv = (acc[t] + bb[t] - mn[t]) * rsqrtf(vr[t] + BN_EPS) * gm[t] + bt[t];
    if (with_act) {
      float rl = fmaxf(vv, 0.f);
      float ge = 0.5f * vv * (1.f + erff(vv * 0.70710678118654752f));
      vv = alpha * rl + (1.f - alpha) * ge;
    }
    acc[t] = vv;
  }
  *(float4*)(out + (size_t)g * D + j)     = make_float4(acc[0], acc[1], acc[2], acc[3]);
  *(float4*)(out + (size_t)g * D + j + 4) = make_float4(acc[4], acc[5], acc[6], acc[7]);
}

// ---------------------------------------------------------------- launch
extern "C" void kernel_launch(void* const* d_in, const int* in_sizes, int n_in,
                              void* d_out, int out_size, void* d_ws, size_t ws_size,
                              hipStream_t stream) {
  const float* x      = (const float*)d_in[0];
  const int*   ei     = (const int*)d_in[1];
  const float* ew     = (const float*)d_in[2];
  const float* W0     = (const float*)d_in[3];
  const float* b0     = (const float*)d_in[4];
  const float* W1     = (const float*)d_in[5];
  const float* b1     = (const float*)d_in[6];
  const float* gamma0 = (const float*)d_in[7];
  const float* beta0  = (const float*)d_in[8];
  const float* mean0  = (const float*)d_in[9];
  const float* var0   = (const float*)d_in[10];
  const float* gamma1 = (const float*)d_in[11];
  const float* beta1  = (const float*)d_in[12];
  const float* mean1  = (const float*)d_in[13];
  const float* var1   = (const float*)d_in[14];
  const float* act    = (const float*)d_in[15];

  const int n = in_sizes[0] / D;
  const int e = in_sizes[2];
  const int* srcp = ei;
  const int* dstp = ei + e;

  // workspace layout
  char* p = (char*)d_ws;
  float* dinv   = (float*)p;  p += sizeof(float) * n;
  int*   off    = (int*)p;    p += sizeof(int) * (n + 1);
  int*   rank   = (int*)p;    p += sizeof(int) * e;
  int*   bsum   = (int*)p;    p += sizeof(int) * 1024;
  uint2* pack   = (uint2*)p;  p += sizeof(uint2) * e;
  __half* h16   = (__half*)p; p += sizeof(__half) * (size_t)n * D;
  float* a      = (float*)p;  p += sizeof(float) * (size_t)n * D;
  float* out    = (float*)d_out;

  const int tpb = 256;
  const int nb_n = (n + tpb - 1) / tpb;
  const int nb_e = (e + tpb - 1) / tpb;
  const int nb_s = (n + 1023) / 1024;          // scan blocks (49)
  const int Gc   = (e + 1023) / 1024;          // count blocks (256 thr x 4 edges)
  const int Gg   = (n + 63) / 64;              // gemm tiles

  // zero counts, then fused {count+rank || gemm0}
  hipMemsetAsync(off, 0, sizeof(int) * (n + 1), stream);
  k_mega0<<<Gc + Gg, tpb, 0, stream>>>(x, W0, h16, dstp, off, rank, n, e, Gc);

  // scan counts -> CSR offsets; scatter edges (no atomics); degrees
  k_scan1<<<nb_s, 1024, 0, stream>>>(off, bsum, n);
  k_scan2<<<1, 1024, 0, stream>>>(bsum, nb_s, off + n);
  k_scan3<<<nb_s, 1024, 0, stream>>>(off, bsum, n);
  k_bucket<<<nb_e, tpb, 0, stream>>>(srcp, dstp, ew, off, rank, pack, e);
  k_degdinv<<<nb_n, tpb, 0, stream>>>(off, pack, dinv, n);

  // ---- layer 0: agg (+bias+BN+blended activation fused)
  k_agg<<<(n + 15) / 16, tpb, 0, stream>>>(h16, off, pack, dinv, b0,
                                           gamma0, beta0, mean0, var0, act, 1, a, n);

  // ---- layer 1: conv -> agg (+bias+BN fused, no activation)
  k_gemm<<<(n + 63) / 64, tpb, 0, stream>>>(a, W1, h16, n);
  k_agg<<<(n + 15) / 16, tpb, 0, stream>>>(h16, off, pack, dinv, b1,
                                           gamma1, beta1, mean1, var1, act, 0, out, n);
}

// Round 6
// 192.756 us; speedup vs baseline: 11.7660x; 1.0164x over previous
//
#include <hip/hip_runtime.h>
#include <hip/hip_fp16.h>
#include <math.h>
#include <type_traits>

#define D 128
#define BN_EPS 1e-5f

// ---------------------------------------------------------------- count + rank
// Counters spread one per 64B cache line to kill same-line atomic serialization.
__global__ void k_cnt_rank(const int* __restrict__ dst, int* cnt16,
                           int* __restrict__ rank, int e) {
  int i = blockIdx.x * blockDim.x + threadIdx.x;
  if (i < e) rank[i] = atomicAdd(&cnt16[(size_t)dst[i] * 16], 1);
}

// ---------------------------------------------------------------- parallel scan
// scan1: read strided counters, write compact exclusive scan into off[].
__global__ __launch_bounds__(1024) void k_scan1(const int* __restrict__ cnt16,
                                                int* __restrict__ off, int* bsum, int n) {
  __shared__ int ws[16];
  const int tid = threadIdx.x;
  const int i = blockIdx.x * 1024 + tid;
  int v = (i < n) ? cnt16[(size_t)i * 16] : 0;
  int x = v;
#pragma unroll
  for (int d = 1; d < 64; d <<= 1) {
    int y = __shfl_up(x, d, 64);
    if ((tid & 63) >= d) x += y;
  }
  const int wid = tid >> 6;
  if ((tid & 63) == 63) ws[wid] = x;
  __syncthreads();
  if (wid == 0) {
    int s = (tid < 16) ? ws[tid] : 0;
#pragma unroll
    for (int d = 1; d < 16; d <<= 1) {
      int y = __shfl_up(s, d, 64);
      if (tid >= d && tid < 16) s += y;
    }
    if (tid < 16) ws[tid] = s;
  }
  __syncthreads();
  int woff = (wid > 0) ? ws[wid - 1] : 0;
  if (i < n) off[i] = woff + x - v;  // exclusive within block
  if (tid == 1023) bsum[blockIdx.x] = ws[15];
}

__global__ __launch_bounds__(1024) void k_scan2(int* bsum, int nb, int* total_loc) {
  __shared__ int ws[16];
  const int tid = threadIdx.x;
  int v = (tid < nb) ? bsum[tid] : 0;
  int x = v;
#pragma unroll
  for (int d = 1; d < 64; d <<= 1) {
    int y = __shfl_up(x, d, 64);
    if ((tid & 63) >= d) x += y;
  }
  const int wid = tid >> 6;
  if ((tid & 63) == 63) ws[wid] = x;
  __syncthreads();
  if (wid == 0) {
    int s = (tid < 16) ? ws[tid] : 0;
#pragma unroll
    for (int d = 1; d < 16; d <<= 1) {
      int y = __shfl_up(s, d, 64);
      if (tid >= d && tid < 16) s += y;
    }
    if (tid < 16) ws[tid] = s;
  }
  __syncthreads();
  int woff = (wid > 0) ? ws[wid - 1] : 0;
  if (tid < nb) bsum[tid] = woff + x - v;
  if (tid == 1023) *total_loc = ws[15];
}

__global__ __launch_bounds__(1024) void k_scan3(int* off, const int* __restrict__ bsum, int n) {
  const int i = blockIdx.x * 1024 + threadIdx.x;
  if (i < n) off[i] += bsum[blockIdx.x];
}

// ---------------------------------------------------------------- bucket scatter (no atomics)
__global__ void k_bucket(const int* __restrict__ src, const int* __restrict__ dst,
                         const float* __restrict__ ew, const int* __restrict__ off,
                         const int* __restrict__ rank, uint2* __restrict__ pack, int e) {
  int i = blockIdx.x * blockDim.x + threadIdx.x;
  if (i < e) {
    int d = dst[i];
    int pos = off[d] + rank[i];
    pack[pos] = make_uint2((unsigned)src[i], __float_as_uint(ew[i]));
  }
}

// ---------------------------------------------------------------- degree -> dinv
__global__ void k_degdinv(const int* __restrict__ off, const uint2* __restrict__ pack,
                          float* __restrict__ dinv, int n) {
  int g = blockIdx.x * blockDim.x + threadIdx.x;
  if (g < n) {
    float deg = 1.0f;  // self-loop weight
    int k1 = off[g + 1];
    for (int k = off[g]; k < k1; ++k) deg += __uint_as_float(pack[k].y);
    dinv[g] = rsqrtf(deg);
  }
}

// ---------------------------------------------------------------- helpers
__device__ __forceinline__ void h8_to_f(const uint4& r, float* f) {
  const __half2* hp = (const __half2*)&r;
#pragma unroll
  for (int t = 0; t < 4; ++t) {
    float2 v = __half22float2(hp[t]);
    f[2 * t] = v.x; f[2 * t + 1] = v.y;
  }
}

// ---------------------------------------------------------------- GEMM H16 = X @ W
// BM=64 x BN=128, BK=32 x 4 phases (LDS 25KB -> 6 blocks/CU). 8x4 register tile.
template <typename T>
__global__ __launch_bounds__(256) void k_gemm(const T* __restrict__ X,
                                              const float* __restrict__ W,
                                              __half* __restrict__ H, int n) {
  __shared__ float sXt[32][68];   // [k][row], padded (row base 272B, 16B-aligned)
  __shared__ float sW[32][128];
  const int tid = threadIdx.x;
  const int tc = tid & 31;
  const int tr = tid >> 5;
  const int row0 = blockIdx.x * 64;

  float acc[8][4];
#pragma unroll
  for (int m = 0; m < 8; ++m)
#pragma unroll
    for (int c = 0; c < 4; ++c) acc[m][c] = 0.f;

  for (int ph = 0; ph < 4; ++ph) {
    const int k0 = ph * 32;
    __syncthreads();
    if constexpr (std::is_same<T, float>::value) {
      for (int i = tid; i < 64 * 8; i += 256) {
        int r = i >> 3, c4 = (i & 7) * 4;
        float4 v = (row0 + r < n)
            ? *(const float4*)(X + (size_t)(row0 + r) * D + k0 + c4)
            : make_float4(0.f, 0.f, 0.f, 0.f);
        sXt[c4 + 0][r] = v.x; sXt[c4 + 1][r] = v.y;
        sXt[c4 + 2][r] = v.z; sXt[c4 + 3][r] = v.w;
      }
    } else {
      for (int i = tid; i < 64 * 4; i += 256) {
        int r = i >> 2, c8 = (i & 3) * 8;
        uint4 u = (row0 + r < n)
            ? *(const uint4*)(X + (size_t)(row0 + r) * D + k0 + c8)
            : make_uint4(0u, 0u, 0u, 0u);
        float f[8];
        h8_to_f(u, f);
#pragma unroll
        for (int t = 0; t < 8; ++t) sXt[c8 + t][r] = f[t];
      }
    }
    for (int i = tid; i < 32 * 32; i += 256) {
      int r = i >> 5, c4 = (i & 31) * 4;
      *(float4*)&sW[r][c4] = *(const float4*)(W + (size_t)(k0 + r) * D + c4);
    }
    __syncthreads();

#pragma unroll 2
    for (int kk = 0; kk < 32; ++kk) {
      float4 a0 = *(const float4*)&sXt[kk][tr * 8];      // broadcast (uniform per half-wave)
      float4 a1 = *(const float4*)&sXt[kk][tr * 8 + 4];
      float4 b = *(const float4*)&sW[kk][tc * 4];        // stride-16B, conflict-free
      float av[8] = { a0.x, a0.y, a0.z, a0.w, a1.x, a1.y, a1.z, a1.w };
      float bv[4] = { b.x, b.y, b.z, b.w };
#pragma unroll
      for (int m = 0; m < 8; ++m)
#pragma unroll
        for (int c = 0; c < 4; ++c) acc[m][c] += av[m] * bv[c];
    }
  }

#pragma unroll
  for (int m = 0; m < 8; ++m) {
    int r = row0 + tr * 8 + m;
    if (r < n) {
      __half2 p0 = __floats2half2_rn(acc[m][0], acc[m][1]);
      __half2 p1 = __floats2half2_rn(acc[m][2], acc[m][3]);
      uint2 st;
      st.x = *(unsigned int*)&p0;
      st.y = *(unsigned int*)&p1;
      *(uint2*)(H + (size_t)r * D + tc * 4) = st;
    }
  }
}

// ------------------------------------------------- fused agg + bias + BN (+act)
// 16-lane group per dst node; lane owns 8 features. 4 edges in flight.
template <typename OutT, bool ACT>
__global__ __launch_bounds__(256) void k_agg(const __half* __restrict__ H,
                                             const int* __restrict__ off,
                                             const uint2* __restrict__ pack,
                                             const float* __restrict__ dinv,
                                             const float* __restrict__ bias,
                                             const float* __restrict__ gamma,
                                             const float* __restrict__ beta,
                                             const float* __restrict__ mean,
                                             const float* __restrict__ var,
                                             const float* __restrict__ act_params,
                                             OutT* __restrict__ out, int n) {
  int g = blockIdx.x * 16 + (threadIdx.x >> 4);
  if (g >= n) return;
  const int j = (threadIdx.x & 15) * 8;  // 8 features per lane

  float acc[8];
#pragma unroll
  for (int t = 0; t < 8; ++t) acc[t] = 0.f;

  int k = off[g], k1 = off[g + 1];
  for (; k + 3 < k1; k += 4) {  // 4 independent gathers in flight
    uint2 p0 = pack[k], p1 = pack[k + 1], p2 = pack[k + 2], p3 = pack[k + 3];
    float w0 = dinv[p0.x] * __uint_as_float(p0.y);
    float w1 = dinv[p1.x] * __uint_as_float(p1.y);
    float w2 = dinv[p2.x] * __uint_as_float(p2.y);
    float w3 = dinv[p3.x] * __uint_as_float(p3.y);
    uint4 r0 = *(const uint4*)(H + (size_t)p0.x * D + j);
    uint4 r1 = *(const uint4*)(H + (size_t)p1.x * D + j);
    uint4 r2 = *(const uint4*)(H + (size_t)p2.x * D + j);
    uint4 r3 = *(const uint4*)(H + (size_t)p3.x * D + j);
    float f0[8], f1[8], f2[8], f3[8];
    h8_to_f(r0, f0); h8_to_f(r1, f1); h8_to_f(r2, f2); h8_to_f(r3, f3);
#pragma unroll
    for (int t = 0; t < 8; ++t)
      acc[t] += w0 * f0[t] + w1 * f1[t] + w2 * f2[t] + w3 * f3[t];
  }
  for (; k < k1; ++k) {
    uint2 p = pack[k];
    float w = dinv[p.x] * __uint_as_float(p.y);
    uint4 r = *(const uint4*)(H + (size_t)p.x * D + j);
    float f[8];
    h8_to_f(r, f);
#pragma unroll
    for (int t = 0; t < 8; ++t) acc[t] += w * f[t];
  }

  float dg = dinv[g];
  uint4 rs = *(const uint4*)(H + (size_t)g * D + j);
  float fs[8];
  h8_to_f(rs, fs);
#pragma unroll
  for (int t = 0; t < 8; ++t) acc[t] = dg * acc[t] + dg * dg * fs[t];

  float bb[8], gm[8], bt[8], mn[8], vr[8];
  *(float4*)&bb[0] = *(const float4*)(bias + j);  *(float4*)&bb[4] = *(const float4*)(bias + j + 4);
  *(float4*)&gm[0] = *(const float4*)(gamma + j); *(float4*)&gm[4] = *(const float4*)(gamma + j + 4);
  *(float4*)&bt[0] = *(const float4*)(beta + j);  *(float4*)&bt[4] = *(const float4*)(beta + j + 4);
  *(float4*)&mn[0] = *(const float4*)(mean + j);  *(float4*)&mn[4] = *(const float4*)(mean + j + 4);
  *(float4*)&vr[0] = *(const float4*)(var + j);   *(float4*)&vr[4] = *(const float4*)(var + j + 4);

  float alpha = ACT ? 1.f / (1.f + expf(-act_params[0])) : 0.f;

#pragma unroll
  for (int t = 0; t < 8; ++t) {
    float vv = (acc[t] + bb[t] - mn[t]) * rsqrtf(vr[t] + BN_EPS) * gm[t] + bt[t];
    if (ACT) {
      float rl = fmaxf(vv, 0.f);
      float ge = 0.5f * vv * (1.f + erff(vv * 0.70710678118654752f));
      vv = alpha * rl + (1.f - alpha) * ge;
    }
    acc[t] = vv;
  }
  if constexpr (std::is_same<OutT, __half>::value) {
    uint4 st;
    __half2* hp = (__half2*)&st;
    hp[0] = __floats2half2_rn(acc[0], acc[1]);
    hp[1] = __floats2half2_rn(acc[2], acc[3]);
    hp[2] = __floats2half2_rn(acc[4], acc[5]);
    hp[3] = __floats2half2_rn(acc[6], acc[7]);
    *(uint4*)(out + (size_t)g * D + j) = st;
  } else {
    *(float4*)(out + (size_t)g * D + j)     = make_float4(acc[0], acc[1], acc[2], acc[3]);
    *(float4*)(out + (size_t)g * D + j + 4) = make_float4(acc[4], acc[5], acc[6], acc[7]);
  }
}

// ---------------------------------------------------------------- launch
extern "C" void kernel_launch(void* const* d_in, const int* in_sizes, int n_in,
                              void* d_out, int out_size, void* d_ws, size_t ws_size,
                              hipStream_t stream) {
  const float* x      = (const float*)d_in[0];
  const int*   ei     = (const int*)d_in[1];
  const float* ew     = (const float*)d_in[2];
  const float* W0     = (const float*)d_in[3];
  const float* b0     = (const float*)d_in[4];
  const float* W1     = (const float*)d_in[5];
  const float* b1     = (const float*)d_in[6];
  const float* gamma0 = (const float*)d_in[7];
  const float* beta0  = (const float*)d_in[8];
  const float* mean0  = (const float*)d_in[9];
  const float* var0   = (const float*)d_in[10];
  const float* gamma1 = (const float*)d_in[11];
  const float* beta1  = (const float*)d_in[12];
  const float* mean1  = (const float*)d_in[13];
  const float* var1   = (const float*)d_in[14];
  const float* act    = (const float*)d_in[15];

  const int n = in_sizes[0] / D;
  const int e = in_sizes[2];
  const int* srcp = ei;
  const int* dstp = ei + e;

  // workspace layout
  char* p = (char*)d_ws;
  float* dinv   = (float*)p;  p += sizeof(float) * n;
  int*   off    = (int*)p;    p += sizeof(int) * (n + 1);
  int*   rank   = (int*)p;    p += sizeof(int) * e;
  int*   bsum   = (int*)p;    p += sizeof(int) * 1024;
  int*   cnt16  = (int*)p;    p += sizeof(int) * (size_t)n * 16;  // 1 counter / 64B line
  uint2* pack   = (uint2*)p;  p += sizeof(uint2) * e;
  __half* h16   = (__half*)p; p += sizeof(__half) * (size_t)n * D;
  __half* a16   = (__half*)p; p += sizeof(__half) * (size_t)n * D;
  float* out    = (float*)d_out;

  const int tpb = 256;
  const int nb_n = (n + tpb - 1) / tpb;
  const int nb_e = (e + tpb - 1) / tpb;
  const int nb_s = (n + 1023) / 1024;  // scan blocks (49)
  const int Gg   = (n + 63) / 64;      // gemm tiles (782)

  // CSR build: spread-counter count+rank -> scan -> scatter -> degrees
  hipMemsetAsync(cnt16, 0, sizeof(int) * (size_t)n * 16, stream);
  k_cnt_rank<<<nb_e, tpb, 0, stream>>>(dstp, cnt16, rank, e);
  k_scan1<<<nb_s, 1024, 0, stream>>>(cnt16, off, bsum, n);
  k_scan2<<<1, 1024, 0, stream>>>(bsum, nb_s, off + n);
  k_scan3<<<nb_s, 1024, 0, stream>>>(off, bsum, n);
  k_bucket<<<nb_e, tpb, 0, stream>>>(srcp, dstp, ew, off, rank, pack, e);
  k_degdinv<<<nb_n, tpb, 0, stream>>>(off, pack, dinv, n);

  // ---- layer 0: conv -> agg (+bias+BN+blended activation), a in fp16
  k_gemm<float><<<Gg, tpb, 0, stream>>>(x, W0, h16, n);
  k_agg<__half, true><<<(n + 15) / 16, tpb, 0, stream>>>(
      h16, off, pack, dinv, b0, gamma0, beta0, mean0, var0, act, a16, n);

  // ---- layer 1: conv (fp16 in) -> agg (+bias+BN), fp32 out
  k_gemm<__half><<<Gg, tpb, 0, stream>>>(a16, W1, h16, n);
  k_agg<float, false><<<(n + 15) / 16, tpb, 0, stream>>>(
      h16, off, pack, dinv, b1, gamma1, beta1, mean1, var1, act, out, n);
}

// Round 7
// 146.118 us; speedup vs baseline: 15.5215x; 1.3192x over previous
//
#include <hip/hip_runtime.h>
#include <hip/hip_fp16.h>
#include <math.h>
#include <type_traits>

#define D 128
#define BN_EPS 1e-5f

typedef _Float16 half8 __attribute__((ext_vector_type(8)));
typedef float f32x4 __attribute__((ext_vector_type(4)));

// ---------------------------------------------------------------- zero (fast fill)
__global__ void k_zero4(uint4* p, int n4) {
  int i = blockIdx.x * blockDim.x + threadIdx.x;
  if (i < n4) p[i] = make_uint4(0u, 0u, 0u, 0u);
}

// ---------------------------------------------------------------- count + rank
// Counters spread one per 64B cache line to kill same-line atomic serialization.
__global__ void k_cnt_rank(const int* __restrict__ dst, int* cnt16,
                           int* __restrict__ rank, int e) {
  int i = blockIdx.x * blockDim.x + threadIdx.x;
  if (i < e) rank[i] = atomicAdd(&cnt16[(size_t)dst[i] * 16], 1);
}

// ---------------------------------------------------------------- parallel scan
__global__ __launch_bounds__(1024) void k_scan1(const int* __restrict__ cnt16,
                                                int* __restrict__ off, int* bsum, int n) {
  __shared__ int ws[16];
  const int tid = threadIdx.x;
  const int i = blockIdx.x * 1024 + tid;
  int v = (i < n) ? cnt16[(size_t)i * 16] : 0;
  int x = v;
#pragma unroll
  for (int d = 1; d < 64; d <<= 1) {
    int y = __shfl_up(x, d, 64);
    if ((tid & 63) >= d) x += y;
  }
  const int wid = tid >> 6;
  if ((tid & 63) == 63) ws[wid] = x;
  __syncthreads();
  if (wid == 0) {
    int s = (tid < 16) ? ws[tid] : 0;
#pragma unroll
    for (int d = 1; d < 16; d <<= 1) {
      int y = __shfl_up(s, d, 64);
      if (tid >= d && tid < 16) s += y;
    }
    if (tid < 16) ws[tid] = s;
  }
  __syncthreads();
  int woff = (wid > 0) ? ws[wid - 1] : 0;
  if (i < n) off[i] = woff + x - v;  // exclusive within block
  if (tid == 1023) bsum[blockIdx.x] = ws[15];
}

__global__ __launch_bounds__(1024) void k_scan2(int* bsum, int nb, int* total_loc) {
  __shared__ int ws[16];
  const int tid = threadIdx.x;
  int v = (tid < nb) ? bsum[tid] : 0;
  int x = v;
#pragma unroll
  for (int d = 1; d < 64; d <<= 1) {
    int y = __shfl_up(x, d, 64);
    if ((tid & 63) >= d) x += y;
  }
  const int wid = tid >> 6;
  if ((tid & 63) == 63) ws[wid] = x;
  __syncthreads();
  if (wid == 0) {
    int s = (tid < 16) ? ws[tid] : 0;
#pragma unroll
    for (int d = 1; d < 16; d <<= 1) {
      int y = __shfl_up(s, d, 64);
      if (tid >= d && tid < 16) s += y;
    }
    if (tid < 16) ws[tid] = s;
  }
  __syncthreads();
  int woff = (wid > 0) ? ws[wid - 1] : 0;
  if (tid < nb) bsum[tid] = woff + x - v;
  if (tid == 1023) *total_loc = ws[15];
}

__global__ __launch_bounds__(1024) void k_scan3(int* off, const int* __restrict__ bsum, int n) {
  const int i = blockIdx.x * 1024 + threadIdx.x;
  if (i < n) off[i] += bsum[blockIdx.x];
}

// ---------------------------------------------------------------- bucket scatter (no atomics)
__global__ void k_bucket(const int* __restrict__ src, const int* __restrict__ dst,
                         const float* __restrict__ ew, const int* __restrict__ off,
                         const int* __restrict__ rank, uint2* __restrict__ pack, int e) {
  int i = blockIdx.x * blockDim.x + threadIdx.x;
  if (i < e) {
    int d = dst[i];
    int pos = off[d] + rank[i];
    pack[pos] = make_uint2((unsigned)src[i], __float_as_uint(ew[i]));
  }
}

// ---------------------------------------------------------------- degree -> dinv
__global__ void k_degdinv(const int* __restrict__ off, const uint2* __restrict__ pack,
                          float* __restrict__ dinv, int n) {
  int g = blockIdx.x * blockDim.x + threadIdx.x;
  if (g < n) {
    float deg = 1.0f;  // self-loop weight
    int k1 = off[g + 1];
    for (int k = off[g]; k < k1; ++k) deg += __uint_as_float(pack[k].y);
    dinv[g] = rsqrtf(deg);
  }
}

// ---------------------------------------------------------------- W -> MFMA B-fragment pack
// B-fragment layout for v_mfma_f32_16x16x32_f16: lane holds B[k=(lane>>4)*8+i][n=lane&15].
// Packed as [nt*4+ks][lane][8] halves so GEMM loads are lane-major coalesced 16B.
__global__ void k_packW(const float* __restrict__ W0, const float* __restrict__ W1,
                        _Float16* __restrict__ p0, _Float16* __restrict__ p1) {
  const float* W = blockIdx.x ? W1 : W0;
  _Float16* P = blockIdx.x ? p1 : p0;
  for (int idx = threadIdx.x; idx < 32 * 64; idx += 256) {
    int ntks = idx >> 6;        // nt*4 + ks
    int lane = idx & 63;
    int nt = ntks >> 2, ks = ntks & 3;
    int kb = ks * 32 + (lane >> 4) * 8;
    int c = nt * 16 + (lane & 15);
#pragma unroll
    for (int i = 0; i < 8; ++i)
      P[(size_t)idx * 8 + i] = (_Float16)W[(size_t)(kb + i) * D + c];
  }
}

// ---------------------------------------------------------------- MFMA GEMM H16 = X @ W
// 4 waves/block, wave owns 16 rows. Per k-step: 1 A-frag load + 8 B-frag loads + 8 MFMA.
// A-frag: lane holds A[m=lane&15][k=(lane>>4)*8+i] -> contiguous 16B from row-major X.
template <typename T>
__global__ __launch_bounds__(256) void k_gemm_mfma(const T* __restrict__ X,
                                                   const _Float16* __restrict__ Bp,
                                                   __half* __restrict__ H, int n) {
  const int lane = threadIdx.x & 63;
  const int wave = threadIdx.x >> 6;
  const int r0 = blockIdx.x * 64 + wave * 16;
  const int arow = r0 + (lane & 15);
  const int kbase = (lane >> 4) * 8;
  const bool av = arow < n;

  f32x4 acc[8];
#pragma unroll
  for (int t = 0; t < 8; ++t) acc[t] = (f32x4){0.f, 0.f, 0.f, 0.f};

#pragma unroll
  for (int ks = 0; ks < 4; ++ks) {
    half8 a;
    if (av) {
      if constexpr (std::is_same<T, float>::value) {
        const float* ap = X + (size_t)arow * D + ks * 32 + kbase;
        float4 f0 = *(const float4*)ap;
        float4 f1 = *(const float4*)(ap + 4);
        a[0] = (_Float16)f0.x; a[1] = (_Float16)f0.y;
        a[2] = (_Float16)f0.z; a[3] = (_Float16)f0.w;
        a[4] = (_Float16)f1.x; a[5] = (_Float16)f1.y;
        a[6] = (_Float16)f1.z; a[7] = (_Float16)f1.w;
      } else {
        a = *(const half8*)((const __half*)X + (size_t)arow * D + ks * 32 + kbase);
      }
    } else {
#pragma unroll
      for (int i = 0; i < 8; ++i) a[i] = (_Float16)0.f;
    }
#pragma unroll
    for (int nt = 0; nt < 8; ++nt) {
      half8 b = *(const half8*)(Bp + ((size_t)(nt * 4 + ks) * 64 + lane) * 8);
      acc[nt] = __builtin_amdgcn_mfma_f32_16x16x32_f16(a, b, acc[nt], 0, 0, 0);
    }
  }

  // C/D layout: col = lane&15, row = (lane>>4)*4 + reg
  const int rbase = (lane >> 4) * 4;
  const int col = lane & 15;
#pragma unroll
  for (int nt = 0; nt < 8; ++nt) {
#pragma unroll
    for (int j = 0; j < 4; ++j) {
      int rr = r0 + rbase + j;
      if (rr < n) H[(size_t)rr * D + nt * 16 + col] = __float2half(acc[nt][j]);
    }
  }
}

// ---------------------------------------------------------------- helpers
__device__ __forceinline__ void h8_to_f(const uint4& r, float* f) {
  const __half2* hp = (const __half2*)&r;
#pragma unroll
  for (int t = 0; t < 4; ++t) {
    float2 v = __half22float2(hp[t]);
    f[2 * t] = v.x; f[2 * t + 1] = v.y;
  }
}

// ------------------------------------------------- fused agg + bias + BN (+act)
template <typename OutT, bool ACT>
__global__ __launch_bounds__(256) void k_agg(const __half* __restrict__ H,
                                             const int* __restrict__ off,
                                             const uint2* __restrict__ pack,
                                             const float* __restrict__ dinv,
                                             const float* __restrict__ bias,
                                             const float* __restrict__ gamma,
                                             const float* __restrict__ beta,
                                             const float* __restrict__ mean,
                                             const float* __restrict__ var,
                                             const float* __restrict__ act_params,
                                             OutT* __restrict__ out, int n) {
  int g = blockIdx.x * 16 + (threadIdx.x >> 4);
  if (g >= n) return;
  const int j = (threadIdx.x & 15) * 8;  // 8 features per lane

  float acc[8];
#pragma unroll
  for (int t = 0; t < 8; ++t) acc[t] = 0.f;

  int k = off[g], k1 = off[g + 1];
  for (; k + 3 < k1; k += 4) {  // 4 independent gathers in flight
    uint2 p0 = pack[k], p1 = pack[k + 1], p2 = pack[k + 2], p3 = pack[k + 3];
    float w0 = dinv[p0.x] * __uint_as_float(p0.y);
    float w1 = dinv[p1.x] * __uint_as_float(p1.y);
    float w2 = dinv[p2.x] * __uint_as_float(p2.y);
    float w3 = dinv[p3.x] * __uint_as_float(p3.y);
    uint4 r0 = *(const uint4*)(H + (size_t)p0.x * D + j);
    uint4 r1 = *(const uint4*)(H + (size_t)p1.x * D + j);
    uint4 r2 = *(const uint4*)(H + (size_t)p2.x * D + j);
    uint4 r3 = *(const uint4*)(H + (size_t)p3.x * D + j);
    float f0[8], f1[8], f2[8], f3[8];
    h8_to_f(r0, f0); h8_to_f(r1, f1); h8_to_f(r2, f2); h8_to_f(r3, f3);
#pragma unroll
    for (int t = 0; t < 8; ++t)
      acc[t] += w0 * f0[t] + w1 * f1[t] + w2 * f2[t] + w3 * f3[t];
  }
  for (; k < k1; ++k) {
    uint2 p = pack[k];
    float w = dinv[p.x] * __uint_as_float(p.y);
    uint4 r = *(const uint4*)(H + (size_t)p.x * D + j);
    float f[8];
    h8_to_f(r, f);
#pragma unroll
    for (int t = 0; t < 8; ++t) acc[t] += w * f[t];
  }

  float dg = dinv[g];
  uint4 rs = *(const uint4*)(H + (size_t)g * D + j);
  float fs[8];
  h8_to_f(rs, fs);
#pragma unroll
  for (int t = 0; t < 8; ++t) acc[t] = dg * acc[t] + dg * dg * fs[t];

  float bb[8], gm[8], bt[8], mn[8], vr[8];
  *(float4*)&bb[0] = *(const float4*)(bias + j);  *(float4*)&bb[4] = *(const float4*)(bias + j + 4);
  *(float4*)&gm[0] = *(const float4*)(gamma + j); *(float4*)&gm[4] = *(const float4*)(gamma + j + 4);
  *(float4*)&bt[0] = *(const float4*)(beta + j);  *(float4*)&bt[4] = *(const float4*)(beta + j + 4);
  *(float4*)&mn[0] = *(const float4*)(mean + j);  *(float4*)&mn[4] = *(const float4*)(mean + j + 4);
  *(float4*)&vr[0] = *(const float4*)(var + j);   *(float4*)&vr[4] = *(const float4*)(var + j + 4);

  float alpha = ACT ? 1.f / (1.f + expf(-act_params[0])) : 0.f;

#pragma unroll
  for (int t = 0; t < 8; ++t) {
    float vv = (acc[t] + bb[t] - mn[t]) * rsqrtf(vr[t] + BN_EPS) * gm[t] + bt[t];
    if (ACT) {
      float rl = fmaxf(vv, 0.f);
      float ge = 0.5f * vv * (1.f + erff(vv * 0.70710678118654752f));
      vv = alpha * rl + (1.f - alpha) * ge;
    }
    acc[t] = vv;
  }
  if constexpr (std::is_same<OutT, __half>::value) {
    uint4 st;
    __half2* hp = (__half2*)&st;
    hp[0] = __floats2half2_rn(acc[0], acc[1]);
    hp[1] = __floats2half2_rn(acc[2], acc[3]);
    hp[2] = __floats2half2_rn(acc[4], acc[5]);
    hp[3] = __floats2half2_rn(acc[6], acc[7]);
    *(uint4*)(out + (size_t)g * D + j) = st;
  } else {
    *(float4*)(out + (size_t)g * D + j)     = make_float4(acc[0], acc[1], acc[2], acc[3]);
    *(float4*)(out + (size_t)g * D + j + 4) = make_float4(acc[4], acc[5], acc[6], acc[7]);
  }
}

// ---------------------------------------------------------------- launch
extern "C" void kernel_launch(void* const* d_in, const int* in_sizes, int n_in,
                              void* d_out, int out_size, void* d_ws, size_t ws_size,
                              hipStream_t stream) {
  const float* x      = (const float*)d_in[0];
  const int*   ei     = (const int*)d_in[1];
  const float* ew     = (const float*)d_in[2];
  const float* W0     = (const float*)d_in[3];
  const float* b0     = (const float*)d_in[4];
  const float* W1     = (const float*)d_in[5];
  const float* b1     = (const float*)d_in[6];
  const float* gamma0 = (const float*)d_in[7];
  const float* beta0  = (const float*)d_in[8];
  const float* mean0  = (const float*)d_in[9];
  const float* var0   = (const float*)d_in[10];
  const float* gamma1 = (const float*)d_in[11];
  const float* beta1  = (const float*)d_in[12];
  const float* mean1  = (const float*)d_in[13];
  const float* var1   = (const float*)d_in[14];
  const float* act    = (const float*)d_in[15];

  const int n = in_sizes[0] / D;
  const int e = in_sizes[2];
  const int* srcp = ei;
  const int* dstp = ei + e;

  // workspace layout (256B-aligned carve-up)
  uintptr_t p = (uintptr_t)d_ws;
  auto carve = [&p](size_t bytes) -> void* {
    void* r = (void*)p;
    p += (bytes + 255) & ~(size_t)255;
    return r;
  };
  float*    dinv  = (float*)carve(sizeof(float) * n);
  int*      off   = (int*)carve(sizeof(int) * (n + 1));
  int*      rank  = (int*)carve(sizeof(int) * e);
  int*      bsum  = (int*)carve(sizeof(int) * 1024);
  int*      cnt16 = (int*)carve(sizeof(int) * (size_t)n * 16);
  _Float16* w0p   = (_Float16*)carve(sizeof(_Float16) * 32 * 64 * 8);
  _Float16* w1p   = (_Float16*)carve(sizeof(_Float16) * 32 * 64 * 8);
  uint2*    pack  = (uint2*)carve(sizeof(uint2) * e);
  __half*   h16   = (__half*)carve(sizeof(__half) * (size_t)n * D);
  __half*   a16   = (__half*)carve(sizeof(__half) * (size_t)n * D);
  float*    out   = (float*)d_out;

  const int tpb = 256;
  const int nb_n = (n + tpb - 1) / tpb;
  const int nb_e = (e + tpb - 1) / tpb;
  const int nb_s = (n + 1023) / 1024;  // scan blocks (49)
  const int Gg   = (n + 63) / 64;      // gemm blocks (782)
  const int nz4  = n * 4;              // n*16 ints = n*4 uint4s

  // CSR build: zero -> count+rank -> scan -> scatter -> degrees; pack W fragments
  k_zero4<<<(nz4 + tpb - 1) / tpb, tpb, 0, stream>>>((uint4*)cnt16, nz4);
  k_packW<<<2, tpb, 0, stream>>>(W0, W1, w0p, w1p);
  k_cnt_rank<<<nb_e, tpb, 0, stream>>>(dstp, cnt16, rank, e);
  k_scan1<<<nb_s, 1024, 0, stream>>>(cnt16, off, bsum, n);
  k_scan2<<<1, 1024, 0, stream>>>(bsum, nb_s, off + n);
  k_scan3<<<nb_s, 1024, 0, stream>>>(off, bsum, n);
  k_bucket<<<nb_e, tpb, 0, stream>>>(srcp, dstp, ew, off, rank, pack, e);
  k_degdinv<<<nb_n, tpb, 0, stream>>>(off, pack, dinv, n);

  // ---- layer 0: MFMA conv (fp32 in) -> agg (+bias+BN+act), a in fp16
  k_gemm_mfma<float><<<Gg, tpb, 0, stream>>>(x, w0p, h16, n);
  k_agg<__half, true><<<(n + 15) / 16, tpb, 0, stream>>>(
      h16, off, pack, dinv, b0, gamma0, beta0, mean0, var0, act, a16, n);

  // ---- layer 1: MFMA conv (fp16 in) -> agg (+bias+BN), fp32 out
  k_gemm_mfma<__half><<<Gg, tpb, 0, stream>>>(a16, w1p, h16, n);
  k_agg<float, false><<<(n + 15) / 16, tpb, 0, stream>>>(
      h16, off, pack, dinv, b1, gamma1, beta1, mean1, var1, act, out, n);
}

// Round 8
// 129.466 us; speedup vs baseline: 17.5180x; 1.1286x over previous
//
#include <hip/hip_runtime.h>
#include <hip/hip_fp16.h>
#include <math.h>
#include <type_traits>

#define D 128
#define BN_EPS 1e-5f

typedef _Float16 half8 __attribute__((ext_vector_type(8)));
typedef float f32x4 __attribute__((ext_vector_type(4)));

// ---------------------------------------------------------------- init: zero cnt16 + pack W
// B-fragment layout for v_mfma_f32_16x16x32_f16: lane holds B[k=(lane>>4)*8+i][n=lane&15].
// Packed as [nt*4+ks][lane][8] halves so GEMM loads are lane-major coalesced 16B.
__global__ void k_init(uint4* __restrict__ z, int n4,
                       const float* __restrict__ W0, const float* __restrict__ W1,
                       _Float16* __restrict__ p0, _Float16* __restrict__ p1, int Z) {
  if ((int)blockIdx.x < Z) {
    int i = blockIdx.x * 256 + threadIdx.x;
    if (i < n4) z[i] = make_uint4(0u, 0u, 0u, 0u);
    return;
  }
  const float* W = (blockIdx.x - Z) ? W1 : W0;
  _Float16* P = (blockIdx.x - Z) ? p1 : p0;
  for (int idx = threadIdx.x; idx < 32 * 64; idx += 256) {
    int ntks = idx >> 6;        // nt*4 + ks
    int lane = idx & 63;
    int nt = ntks >> 2, ks = ntks & 3;
    int kb = ks * 32 + (lane >> 4) * 8;
    int c = nt * 16 + (lane & 15);
#pragma unroll
    for (int i = 0; i < 8; ++i)
      P[(size_t)idx * 8 + i] = (_Float16)W[(size_t)(kb + i) * D + c];
  }
}

// ---------------------------------------------------------------- count+rank || gemm0 (MFMA)
// Count blocks: spread counters (1 per 64B line). Gemm blocks: no LDS, register MFMA.
__global__ __launch_bounds__(256) void k_cnt_gemm0(const float* __restrict__ X,
                                                   const _Float16* __restrict__ Bp,
                                                   __half* __restrict__ H,
                                                   const int* __restrict__ dst,
                                                   int* cnt16, int* __restrict__ rank,
                                                   int n, int e, int Gc) {
  if ((int)blockIdx.x < Gc) {
    int base = blockIdx.x * 1024 + threadIdx.x;
#pragma unroll
    for (int jj = 0; jj < 4; ++jj) {
      int i = base + jj * 256;
      if (i < e) rank[i] = atomicAdd(&cnt16[(size_t)dst[i] * 16], 1);
    }
    return;
  }

  const int lane = threadIdx.x & 63;
  const int wave = threadIdx.x >> 6;
  const int r0 = (blockIdx.x - Gc) * 64 + wave * 16;
  const int arow = r0 + (lane & 15);
  const int kbase = (lane >> 4) * 8;
  const bool av = arow < n;

  f32x4 acc[8];
#pragma unroll
  for (int t = 0; t < 8; ++t) acc[t] = (f32x4){0.f, 0.f, 0.f, 0.f};

#pragma unroll
  for (int ks = 0; ks < 4; ++ks) {
    half8 a;
    if (av) {
      const float* ap = X + (size_t)arow * D + ks * 32 + kbase;
      float4 f0 = *(const float4*)ap;
      float4 f1 = *(const float4*)(ap + 4);
      a[0] = (_Float16)f0.x; a[1] = (_Float16)f0.y;
      a[2] = (_Float16)f0.z; a[3] = (_Float16)f0.w;
      a[4] = (_Float16)f1.x; a[5] = (_Float16)f1.y;
      a[6] = (_Float16)f1.z; a[7] = (_Float16)f1.w;
    } else {
#pragma unroll
      for (int i = 0; i < 8; ++i) a[i] = (_Float16)0.f;
    }
#pragma unroll
    for (int nt = 0; nt < 8; ++nt) {
      half8 b = *(const half8*)(Bp + ((size_t)(nt * 4 + ks) * 64 + lane) * 8);
      acc[nt] = __builtin_amdgcn_mfma_f32_16x16x32_f16(a, b, acc[nt], 0, 0, 0);
    }
  }

  // C/D layout: col = lane&15, row = (lane>>4)*4 + reg
  const int rbase = (lane >> 4) * 4;
  const int col = lane & 15;
#pragma unroll
  for (int nt = 0; nt < 8; ++nt) {
#pragma unroll
    for (int j = 0; j < 4; ++j) {
      int rr = r0 + rbase + j;
      if (rr < n) H[(size_t)rr * D + nt * 16 + col] = __float2half(acc[nt][j]);
    }
  }
}

// ---------------------------------------------------------------- scan phase 1
__global__ __launch_bounds__(1024) void k_scan1(const int* __restrict__ cnt16,
                                                int* __restrict__ off, int* bsum, int n) {
  __shared__ int ws[16];
  const int tid = threadIdx.x;
  const int i = blockIdx.x * 1024 + tid;
  int v = (i < n) ? cnt16[(size_t)i * 16] : 0;
  int x = v;
#pragma unroll
  for (int d = 1; d < 64; d <<= 1) {
    int y = __shfl_up(x, d, 64);
    if ((tid & 63) >= d) x += y;
  }
  const int wid = tid >> 6;
  if ((tid & 63) == 63) ws[wid] = x;
  __syncthreads();
  if (wid == 0) {
    int s = (tid < 16) ? ws[tid] : 0;
#pragma unroll
    for (int d = 1; d < 16; d <<= 1) {
      int y = __shfl_up(s, d, 64);
      if (tid >= d && tid < 16) s += y;
    }
    if (tid < 16) ws[tid] = s;
  }
  __syncthreads();
  int woff = (wid > 0) ? ws[wid - 1] : 0;
  if (i < n) off[i] = woff + x - v;  // exclusive within block
  if (tid == 1023) bsum[blockIdx.x] = ws[15];
}

// ---------------------------------------------------------------- scan phases 2+3 fused
// Each block re-scans the (<=64) block sums in wave 0, adds its prefix. nb <= 64 required.
__global__ __launch_bounds__(1024) void k_scan23(int* off, const int* __restrict__ bsum,
                                                 int n, int nb) {
  __shared__ int sh[2];
  const int tid = threadIdx.x;
  if (tid < 64) {
    int x = (tid < nb) ? bsum[tid] : 0;
#pragma unroll
    for (int d = 1; d < 64; d <<= 1) {
      int y = __shfl_up(x, d, 64);
      if (tid >= d) x += y;
    }
    int pfx = (blockIdx.x > 0) ? __shfl(x, (int)blockIdx.x - 1, 64) : 0;
    int tot = __shfl(x, nb - 1, 64);
    if (tid == 0) { sh[0] = pfx; sh[1] = tot; }
  }
  __syncthreads();
  const int i = blockIdx.x * 1024 + tid;
  if (i < n) off[i] += sh[0];
  if (blockIdx.x == 0 && tid == 0) off[n] = sh[1];
}

// ---------------------------------------------------------------- bucket scatter (no atomics)
__global__ void k_bucket(const int* __restrict__ src, const int* __restrict__ dst,
                         const float* __restrict__ ew, const int* __restrict__ off,
                         const int* __restrict__ rank, uint2* __restrict__ pack, int e) {
  int i = blockIdx.x * blockDim.x + threadIdx.x;
  if (i < e) {
    int d = dst[i];
    int pos = off[d] + rank[i];
    pack[pos] = make_uint2((unsigned)src[i], __float_as_uint(ew[i]));
  }
}

// ---------------------------------------------------------------- degree -> dinv
__global__ void k_degdinv(const int* __restrict__ off, const uint2* __restrict__ pack,
                          float* __restrict__ dinv, int n) {
  int g = blockIdx.x * blockDim.x + threadIdx.x;
  if (g < n) {
    float deg = 1.0f;  // self-loop weight
    int k1 = off[g + 1];
    for (int k = off[g]; k < k1; ++k) deg += __uint_as_float(pack[k].y);
    dinv[g] = rsqrtf(deg);
  }
}

// ---------------------------------------------------------------- helpers
__device__ __forceinline__ void h8_to_f(const uint4& r, float* f) {
  const __half2* hp = (const __half2*)&r;
#pragma unroll
  for (int t = 0; t < 4; ++t) {
    float2 v = __half22float2(hp[t]);
    f[2 * t] = v.x; f[2 * t + 1] = v.y;
  }
}

// agg core: features j..j+7 of node g -> acc[8] (post bias+BN(+act))
template <bool ACT>
__device__ __forceinline__ void agg_node(const __half* __restrict__ H,
                                         const int* __restrict__ off,
                                         const uint2* __restrict__ pack,
                                         const float* __restrict__ dinv,
                                         const float* __restrict__ bias,
                                         const float* __restrict__ gamma,
                                         const float* __restrict__ beta,
                                         const float* __restrict__ mean,
                                         const float* __restrict__ var,
                                         float alpha, int g, int j, float* acc) {
#pragma unroll
  for (int t = 0; t < 8; ++t) acc[t] = 0.f;

  int k = off[g], k1 = off[g + 1];
  for (; k + 3 < k1; k += 4) {  // 4 independent gathers in flight
    uint2 p0 = pack[k], p1 = pack[k + 1], p2 = pack[k + 2], p3 = pack[k + 3];
    float w0 = dinv[p0.x] * __uint_as_float(p0.y);
    float w1 = dinv[p1.x] * __uint_as_float(p1.y);
    float w2 = dinv[p2.x] * __uint_as_float(p2.y);
    float w3 = dinv[p3.x] * __uint_as_float(p3.y);
    uint4 r0 = *(const uint4*)(H + (size_t)p0.x * D + j);
    uint4 r1 = *(const uint4*)(H + (size_t)p1.x * D + j);
    uint4 r2 = *(const uint4*)(H + (size_t)p2.x * D + j);
    uint4 r3 = *(const uint4*)(H + (size_t)p3.x * D + j);
    float f0[8], f1[8], f2[8], f3[8];
    h8_to_f(r0, f0); h8_to_f(r1, f1); h8_to_f(r2, f2); h8_to_f(r3, f3);
#pragma unroll
    for (int t = 0; t < 8; ++t)
      acc[t] += w0 * f0[t] + w1 * f1[t] + w2 * f2[t] + w3 * f3[t];
  }
  for (; k < k1; ++k) {
    uint2 p = pack[k];
    float w = dinv[p.x] * __uint_as_float(p.y);
    uint4 r = *(const uint4*)(H + (size_t)p.x * D + j);
    float f[8];
    h8_to_f(r, f);
#pragma unroll
    for (int t = 0; t < 8; ++t) acc[t] += w * f[t];
  }

  float dg = dinv[g];
  uint4 rs = *(const uint4*)(H + (size_t)g * D + j);
  float fs[8];
  h8_to_f(rs, fs);
#pragma unroll
  for (int t = 0; t < 8; ++t) acc[t] = dg * acc[t] + dg * dg * fs[t];

  float bb[8], gm[8], bt[8], mn[8], vr[8];
  *(float4*)&bb[0] = *(const float4*)(bias + j);  *(float4*)&bb[4] = *(const float4*)(bias + j + 4);
  *(float4*)&gm[0] = *(const float4*)(gamma + j); *(float4*)&gm[4] = *(const float4*)(gamma + j + 4);
  *(float4*)&bt[0] = *(const float4*)(beta + j);  *(float4*)&bt[4] = *(const float4*)(beta + j + 4);
  *(float4*)&mn[0] = *(const float4*)(mean + j);  *(float4*)&mn[4] = *(const float4*)(mean + j + 4);
  *(float4*)&vr[0] = *(const float4*)(var + j);   *(float4*)&vr[4] = *(const float4*)(var + j + 4);

#pragma unroll
  for (int t = 0; t < 8; ++t) {
    float vv = (acc[t] + bb[t] - mn[t]) * rsqrtf(vr[t] + BN_EPS) * gm[t] + bt[t];
    if (ACT) {
      float rl = fmaxf(vv, 0.f);
      float ge = 0.5f * vv * (1.f + erff(vv * 0.70710678118654752f));
      vv = alpha * rl + (1.f - alpha) * ge;
    }
    acc[t] = vv;
  }
}

// ------------------------------------------------- fused agg0(+BN+act) -> LDS -> MFMA gemm1
// 32 nodes/block. Phase A: 16 groups of 16 lanes aggregate 2 nodes each into sA (fp16,
// pad 136 -> 2-way LDS conflicts only). Phase B: 4 waves MFMA (2 row-halves x 2 nt-halves).
__global__ __launch_bounds__(256) void k_agg_gemm(const __half* __restrict__ H,
                                                  const int* __restrict__ off,
                                                  const uint2* __restrict__ pack,
                                                  const float* __restrict__ dinv,
                                                  const float* __restrict__ bias,
                                                  const float* __restrict__ gamma,
                                                  const float* __restrict__ beta,
                                                  const float* __restrict__ mean,
                                                  const float* __restrict__ var,
                                                  const float* __restrict__ act_params,
                                                  const _Float16* __restrict__ Bp,
                                                  __half* __restrict__ Hout, int n) {
  __shared__ _Float16 sA[32][136];
  const int tid = threadIdx.x;
  const int row0 = blockIdx.x * 32;
  const int grp = tid >> 4;
  const int j = (tid & 15) * 8;
  const float alpha = 1.f / (1.f + expf(-act_params[0]));

#pragma unroll
  for (int it = 0; it < 2; ++it) {
    int lr = it * 16 + grp;
    int g = row0 + lr;
    half8 st;
    if (g < n) {
      float acc[8];
      agg_node<true>(H, off, pack, dinv, bias, gamma, beta, mean, var, alpha, g, j, acc);
#pragma unroll
      for (int t = 0; t < 8; ++t) st[t] = (_Float16)acc[t];
    } else {
#pragma unroll
      for (int t = 0; t < 8; ++t) st[t] = (_Float16)0.f;
    }
    *(half8*)&sA[lr][j] = st;
  }
  __syncthreads();

  // Phase B: wave w -> local rows (w&1)*16, nt tiles (w>>1)*4 .. +3
  const int lane = tid & 63;
  const int wave = tid >> 6;
  const int lrow = (wave & 1) * 16;
  const int ntb = (wave >> 1) * 4;
  const int arowl = lrow + (lane & 15);
  const int kbase = (lane >> 4) * 8;

  f32x4 acc[4];
#pragma unroll
  for (int t = 0; t < 4; ++t) acc[t] = (f32x4){0.f, 0.f, 0.f, 0.f};

#pragma unroll
  for (int ks = 0; ks < 4; ++ks) {
    half8 a = *(const half8*)&sA[arowl][ks * 32 + kbase];
#pragma unroll
    for (int nt = 0; nt < 4; ++nt) {
      half8 b = *(const half8*)(Bp + ((size_t)((ntb + nt) * 4 + ks) * 64 + lane) * 8);
      acc[nt] = __builtin_amdgcn_mfma_f32_16x16x32_f16(a, b, acc[nt], 0, 0, 0);
    }
  }

  const int rbase = (lane >> 4) * 4;
  const int col = lane & 15;
#pragma unroll
  for (int nt = 0; nt < 4; ++nt) {
#pragma unroll
    for (int jj = 0; jj < 4; ++jj) {
      int rr = row0 + lrow + rbase + jj;
      if (rr < n) Hout[(size_t)rr * D + (ntb + nt) * 16 + col] = __float2half(acc[nt][jj]);
    }
  }
}

// ------------------------------------------------- standalone agg (layer 1 -> fp32 out)
template <typename OutT, bool ACT>
__global__ __launch_bounds__(256) void k_agg(const __half* __restrict__ H,
                                             const int* __restrict__ off,
                                             const uint2* __restrict__ pack,
                                             const float* __restrict__ dinv,
                                             const float* __restrict__ bias,
                                             const float* __restrict__ gamma,
                                             const float* __restrict__ beta,
                                             const float* __restrict__ mean,
                                             const float* __restrict__ var,
                                             const float* __restrict__ act_params,
                                             OutT* __restrict__ out, int n) {
  int g = blockIdx.x * 16 + (threadIdx.x >> 4);
  if (g >= n) return;
  const int j = (threadIdx.x & 15) * 8;
  const float alpha = ACT ? 1.f / (1.f + expf(-act_params[0])) : 0.f;

  float acc[8];
  agg_node<ACT>(H, off, pack, dinv, bias, gamma, beta, mean, var, alpha, g, j, acc);

  if constexpr (std::is_same<OutT, __half>::value) {
    uint4 st;
    __half2* hp = (__half2*)&st;
    hp[0] = __floats2half2_rn(acc[0], acc[1]);
    hp[1] = __floats2half2_rn(acc[2], acc[3]);
    hp[2] = __floats2half2_rn(acc[4], acc[5]);
    hp[3] = __floats2half2_rn(acc[6], acc[7]);
    *(uint4*)(out + (size_t)g * D + j) = st;
  } else {
    *(float4*)(out + (size_t)g * D + j)     = make_float4(acc[0], acc[1], acc[2], acc[3]);
    *(float4*)(out + (size_t)g * D + j + 4) = make_float4(acc[4], acc[5], acc[6], acc[7]);
  }
}

// ---------------------------------------------------------------- launch
extern "C" void kernel_launch(void* const* d_in, const int* in_sizes, int n_in,
                              void* d_out, int out_size, void* d_ws, size_t ws_size,
                              hipStream_t stream) {
  const float* x      = (const float*)d_in[0];
  const int*   ei     = (const int*)d_in[1];
  const float* ew     = (const float*)d_in[2];
  const float* W0     = (const float*)d_in[3];
  const float* b0     = (const float*)d_in[4];
  const float* W1     = (const float*)d_in[5];
  const float* b1     = (const float*)d_in[6];
  const float* gamma0 = (const float*)d_in[7];
  const float* beta0  = (const float*)d_in[8];
  const float* mean0  = (const float*)d_in[9];
  const float* var0   = (const float*)d_in[10];
  const float* gamma1 = (const float*)d_in[11];
  const float* beta1  = (const float*)d_in[12];
  const float* mean1  = (const float*)d_in[13];
  const float* var1   = (const float*)d_in[14];
  const float* act    = (const float*)d_in[15];

  const int n = in_sizes[0] / D;
  const int e = in_sizes[2];
  const int* srcp = ei;
  const int* dstp = ei + e;

  // workspace layout (256B-aligned carve-up)
  uintptr_t p = (uintptr_t)d_ws;
  auto carve = [&p](size_t bytes) -> void* {
    void* r = (void*)p;
    p += (bytes + 255) & ~(size_t)255;
    return r;
  };
  float*    dinv  = (float*)carve(sizeof(float) * n);
  int*      off   = (int*)carve(sizeof(int) * (n + 1));
  int*      rank  = (int*)carve(sizeof(int) * e);
  int*      bsum  = (int*)carve(sizeof(int) * 1024);
  int*      cnt16 = (int*)carve(sizeof(int) * (size_t)n * 16);
  _Float16* w0p   = (_Float16*)carve(sizeof(_Float16) * 32 * 64 * 8);
  _Float16* w1p   = (_Float16*)carve(sizeof(_Float16) * 32 * 64 * 8);
  uint2*    pack  = (uint2*)carve(sizeof(uint2) * e);
  __half*   h16   = (__half*)carve(sizeof(__half) * (size_t)n * D);
  __half*   h16b  = (__half*)carve(sizeof(__half) * (size_t)n * D);
  float*    out   = (float*)d_out;

  const int tpb = 256;
  const int nb_n = (n + tpb - 1) / tpb;
  const int nb_e = (e + tpb - 1) / tpb;
  const int nb_s = (n + 1023) / 1024;  // scan blocks (49; k_scan23 requires <= 64)
  const int Gc   = (e + 1023) / 1024;  // count blocks
  const int Gg   = (n + 63) / 64;      // gemm0 blocks
  const int nz4  = n * 4;              // n*16 ints = n*4 uint4s
  const int Z    = (nz4 + tpb - 1) / tpb;

  // init (zero + packW) -> {count+rank || gemm0} -> scan -> scatter -> degrees
  k_init<<<Z + 2, tpb, 0, stream>>>((uint4*)cnt16, nz4, W0, W1, w0p, w1p, Z);
  k_cnt_gemm0<<<Gc + Gg, tpb, 0, stream>>>(x, w0p, h16, dstp, cnt16, rank, n, e, Gc);
  k_scan1<<<nb_s, 1024, 0, stream>>>(cnt16, off, bsum, n);
  k_scan23<<<nb_s, 1024, 0, stream>>>(off, bsum, n, nb_s);
  k_bucket<<<nb_e, tpb, 0, stream>>>(srcp, dstp, ew, off, rank, pack, e);
  k_degdinv<<<nb_n, tpb, 0, stream>>>(off, pack, dinv, n);

  // layer 0 agg (+BN+act) fused with layer 1 conv
  k_agg_gemm<<<(n + 31) / 32, tpb, 0, stream>>>(
      h16, off, pack, dinv, b0, gamma0, beta0, mean0, var0, act, w1p, h16b, n);

  // layer 1 agg (+BN), fp32 out
  k_agg<float, false><<<(n + 15) / 16, tpb, 0, stream>>>(
      h16b, off, pack, dinv, b1, gamma1, beta1, mean1, var1, act, out, n);
}